// Round 15
// baseline (295.308 us; speedup 1.0000x reference)
//
#include <hip/hip_runtime.h>
#include <hip/hip_bf16.h>
#include <cstdint>
#include <cmath>

#define DEV static __device__ __forceinline__

typedef __attribute__((ext_vector_type(8))) short bf16x8;
typedef __attribute__((ext_vector_type(4))) float f32x4;

DEV ushort f2bf(float f) {
    union { float f; uint32_t u; } v; v.f = f;
    uint32_t r = v.u + 0x7FFFu + ((v.u >> 16) & 1u);
    return (ushort)(r >> 16);
}
DEV uint32_t pack2bf(float lo, float hi) {
    return (uint32_t)f2bf(lo) | ((uint32_t)f2bf(hi) << 16);
}
DEV float bf2f(ushort h) {
    union { uint32_t u; float f; } v; v.u = ((uint32_t)h) << 16;
    return v.f;
}
// async global->LDS, 16B per lane; LDS dest = wave-uniform base + lane*16
DEV void gld16(const ushort* g, ushort* l) {
    __builtin_amdgcn_global_load_lds(
        (const __attribute__((address_space(1))) unsigned int*)g,
        (__attribute__((address_space(3))) unsigned int*)l, 16, 0, 0);
}

DEV float2 block_reduce2(float a, float b, float2* red, int tid) {
    red[tid] = make_float2(a, b);
    __syncthreads();
    for (int s2 = 128; s2 > 0; s2 >>= 1) {
        if (tid < s2) {
            float2 o = red[tid + s2];
            float2 m = red[tid];
            red[tid] = make_float2(m.x + o.x, m.y + o.y);
        }
        __syncthreads();
    }
    float2 r = red[0];
    __syncthreads();
    return r;
}

// ---------------- x f32 -> bf16 cast (coalesced, 8 elems/thread) ----------------
__global__ __launch_bounds__(256)
void xcast_k(const float* __restrict__ x, ushort* __restrict__ xb)
{
    const size_t i = (size_t)blockIdx.x * 256 + threadIdx.x;
    const float4* s = (const float4*)(x + i * 8);
    float4 a = s[0], b = s[1];
    uint4 o;
    o.x = pack2bf(a.x, a.y); o.y = pack2bf(a.z, a.w);
    o.z = pack2bf(b.x, b.y); o.w = pack2bf(b.z, b.w);
    *(uint4*)(xb + i * 8) = o;
}

// ---------------- prep: cls = cls0 + E@E2D_w + E2D_b ; clsln = LN(cls) ----------------
__global__ __launch_bounds__(256)
void prep_cls_k(const float* __restrict__ E, const float* __restrict__ cls0,
                const float* __restrict__ w, const float* __restrict__ bb,
                const float* __restrict__ g, const float* __restrict__ be,
                float* __restrict__ cls, ushort* __restrict__ clsln)
{
    const int k = blockIdx.x, tid = threadIdx.x;
    __shared__ float Ek[16];
    if (tid < 16) Ek[tid] = E[k * 16 + tid];
    __syncthreads();
    float vals[2];
#pragma unroll
    for (int j = 0; j < 2; j++) {
        int d = tid + j * 256;
        float a = cls0[k * 512 + d] + bb[d];
#pragma unroll
        for (int e = 0; e < 16; e++) a += Ek[e] * w[e * 512 + d];
        vals[j] = a;
        cls[k * 512 + d] = a;
    }
    __shared__ float2 red[256];
    float2 sr = block_reduce2(vals[0] + vals[1], vals[0] * vals[0] + vals[1] * vals[1], red, tid);
    float mu = sr.x * (1.f / 512.f);
    float var = sr.y * (1.f / 512.f) - mu * mu;
    float inv = rsqrtf(var + 1e-5f);
#pragma unroll
    for (int j = 0; j < 2; j++) {
        int d = tid + j * 256;
        clsln[k * 512 + d] = f2bf((vals[j] - mu) * inv * g[d] + be[d]);
    }
}

// ---------------- prep: q = clsln @ Wq + b (64x512x512, tiny) ----------------
__global__ __launch_bounds__(512)
void prep_q_k(const ushort* __restrict__ clsln, const float* __restrict__ wq,
              const float* __restrict__ wqb, ushort* __restrict__ qbf)
{
    const int kb = blockIdx.x * 4;
    const int n = threadIdx.x;
    __shared__ float Ar[4][512];
#pragma unroll
    for (int j = 0; j < 4; j++) Ar[j][n] = bf2f(clsln[(kb + j) * 512 + n]);
    __syncthreads();
    float acc[4] = {0.f, 0.f, 0.f, 0.f};
    for (int d = 0; d < 512; ++d) {
        float wv = wq[d * 512 + n];
#pragma unroll
        for (int j = 0; j < 4; j++) acc[j] += Ar[j][d] * wv;
    }
#pragma unroll
    for (int j = 0; j < 4; j++) qbf[(kb + j) * 512 + n] = f2bf(acc[j] + wqb[n]);
}

// ---------------- batched weight prep: 4 transposes + bias pack in ONE launch ----------------
__global__ __launch_bounds__(256)
void wprep_k(const float* __restrict__ wk, const float* __restrict__ wv,
             const float* __restrict__ fc1w, const float* __restrict__ fc2w,
             const float* __restrict__ kb, const float* __restrict__ vb,
             ushort* __restrict__ wkvt, ushort* __restrict__ fc1t,
             ushort* __restrict__ fc2t, float* __restrict__ biaskv)
{
    const int id = blockIdx.x;
    if (id >= 2560) {
        int i = (id - 2560) * 256 + threadIdx.x;
        biaskv[i] = (i < 512) ? kb[i] : vb[i - 512];
        return;
    }
    const float* in; ushort* out; int R, C, bx, by;
    if (id < 256)        { in = wk;   out = wkvt;                  R = 512;  C = 512;  int t = id;        bx = t & 15; by = t >> 4; }
    else if (id < 512)   { in = wv;   out = wkvt + 512 * 512;      R = 512;  C = 512;  int t = id - 256;  bx = t & 15; by = t >> 4; }
    else if (id < 1536)  { in = fc1w; out = fc1t;                  R = 512;  C = 2048; int t = id - 512;  bx = t & 63; by = t >> 6; }
    else                 { in = fc2w; out = fc2t;                  R = 2048; C = 512;  int t = id - 1536; bx = t & 15; by = t >> 4; }
    __shared__ float T[32][33];
    const int c0 = bx * 32, r0 = by * 32;
    const int tx = threadIdx.x & 31, ty = threadIdx.x >> 5;
#pragma unroll
    for (int i = 0; i < 32; i += 8)
        T[ty + i][tx] = in[(size_t)(r0 + ty + i) * C + c0 + tx];
    __syncthreads();
#pragma unroll
    for (int i = 0; i < 32; i += 8)
        out[(size_t)(c0 + ty + i) * R + r0 + tx] = f2bf(T[tx][ty + i]);
}

// ---------------- finalize counts: cnt[b*64+k] = sum over 8 s-partials ----------------
__global__ __launch_bounds__(256)
void count_fin_k(const float* __restrict__ cpart, float* __restrict__ cnt,
                 float* __restrict__ emp)
{
    const int i = blockIdx.x * 256 + threadIdx.x;   // 0..1023 = b*64+k
    const float* p = cpart + (size_t)i * 8;
    float s = 0.f;
#pragma unroll
    for (int t = 0; t < 8; t++) s += p[t];
    cnt[i] = s;
    emp[i] = (s <= 1e-6f) ? 1.f : 0.f;
}

// ---------------- 128x128xBK64 bf16 MFMA GEMM, 8 waves (512 thr), single-buffer ----------------
// (r12-best configuration)
template<int AMODE, int EPI, int SWZ, int ND, int KD, int LDK>
__global__ __launch_bounds__(512)
void gemm_k(const void* __restrict__ Ap, const ushort* __restrict__ Bt,
            const float* __restrict__ bias,
            ushort* __restrict__ o_bf, const float* __restrict__ res,
            float* __restrict__ o_f)
{
    __shared__ ushort smem[16384];
    ushort* As = smem;
    ushort* Bs = smem + 8192;
    int m0, n0;
    if (SWZ) {
        int L = blockIdx.x;
        int c = L & 7, j = L >> 3;
        m0 = (c * 64 + (j >> 3)) * 128;
        n0 = (j & 7) * 128;
    } else {
        m0 = blockIdx.x * 128;
        n0 = blockIdx.y * 128;
    }
    const int tid = threadIdx.x;
    const int w = tid >> 6, l = tid & 63;
    const int wr = w >> 2, wc = w & 3;
    const int lg = l >> 4, lr = l & 15;

    const f32x4 fzero = {0.f, 0.f, 0.f, 0.f};
    f32x4 acc[4][2];
#pragma unroll
    for (int i = 0; i < 4; i++)
#pragma unroll
        for (int j = 0; j < 2; j++) acc[i][j] = fzero;

    const int lrow8 = l >> 3;
    const int colswz = ((l & 7) ^ lrow8) * 8;
    const ushort* gB  = Bt + (size_t)(n0 + w * 16 + lrow8) * LDK + colswz;
    const ushort* gA0 = (const ushort*)Ap + (size_t)(m0 + w * 16 + lrow8) * LDK + colswz;
    const float*  gA1 = (const float*)Ap + (size_t)(m0 + w * 16 + (l >> 2)) * LDK + (l & 3) * 16;

    const int kbase = blockIdx.z * KD;
    constexpr int NT = KD / 64;
#pragma unroll
    for (int t = 0; t < NT; ++t) {
        const int kt = kbase + t * 64;
        __syncthreads();
        if (AMODE == 0) {
#pragma unroll
            for (int i = 0; i < 2; i++) {
                gld16(gA0 + (size_t)i * 8 * LDK + kt, As + (w * 16 + i * 8) * 64);
                gld16(gB + (size_t)i * 8 * LDK + kt, Bs + (w * 16 + i * 8) * 64);
            }
        } else {
            float4 av[4];
#pragma unroll
            for (int i = 0; i < 4; i++)
                av[i] = *(const float4*)(gA1 + kt + i * 4);
#pragma unroll
            for (int i = 0; i < 2; i++)
                gld16(gB + (size_t)i * 8 * LDK + kt, Bs + (w * 16 + i * 8) * 64);
            {
                int r = w * 16 + (l >> 2);
                uint2 p0, p1;
                p0.x = pack2bf(av[0].x, av[0].y); p0.y = pack2bf(av[0].z, av[0].w);
                uint2 q0; q0.x = pack2bf(av[1].x, av[1].y); q0.y = pack2bf(av[1].z, av[1].w);
                p1.x = pack2bf(av[2].x, av[2].y); p1.y = pack2bf(av[2].z, av[2].w);
                uint2 q1; q1.x = pack2bf(av[3].x, av[3].y); q1.y = pack2bf(av[3].z, av[3].w);
                int cb = (l & 3) * 32;
                *(uint2*)((char*)As + r * 128 + ((cb     ) ^ ((r & 7) << 4))) = p0;
                *(uint2*)((char*)As + r * 128 + ((cb +  8) ^ ((r & 7) << 4))) = q0;
                *(uint2*)((char*)As + r * 128 + ((cb + 16) ^ ((r & 7) << 4))) = p1;
                *(uint2*)((char*)As + r * 128 + ((cb + 24) ^ ((r & 7) << 4))) = q1;
            }
        }
        asm volatile("s_waitcnt vmcnt(0)" ::: "memory");
        __syncthreads();
#pragma unroll
        for (int kk = 0; kk < 2; kk++) {
            int kb = (kk * 32 + lg * 8) * 2;
            bf16x8 af[4], bfv[2];
#pragma unroll
            for (int mi = 0; mi < 4; mi++) {
                int row = wr * 64 + mi * 16 + lr;
                af[mi] = *(bf16x8*)((char*)As + row * 128 + (kb ^ ((row & 7) << 4)));
            }
#pragma unroll
            for (int ni = 0; ni < 2; ni++) {
                int row = wc * 32 + ni * 16 + lr;
                bfv[ni] = *(bf16x8*)((char*)Bs + row * 128 + (kb ^ ((row & 7) << 4)));
            }
#pragma unroll
            for (int mi = 0; mi < 4; mi++)
#pragma unroll
                for (int ni = 0; ni < 2; ni++)
                    acc[mi][ni] = __builtin_amdgcn_mfma_f32_16x16x32_bf16(af[mi], bfv[ni], acc[mi][ni], 0, 0, 0);
        }
    }

    if (EPI == 0) {
        __syncthreads();
#pragma unroll
        for (int mi = 0; mi < 4; mi++)
#pragma unroll
            for (int ni = 0; ni < 2; ni++)
#pragma unroll
                for (int r = 0; r < 4; r++) {
                    int rl = wr * 64 + mi * 16 + lg * 4 + r;
                    int cl = wc * 32 + ni * 16 + lr;
                    int byteoff = rl * 256 + ((cl * 2) ^ ((rl & 7) << 4));
                    *(ushort*)((char*)smem + byteoff) = f2bf(acc[mi][ni][r] + bias[n0 + cl]);
                }
        __syncthreads();
        const int row = tid >> 2, sg2 = tid & 3;
        uint4* dq = (uint4*)(o_bf + (size_t)(m0 + row) * ND + n0 + sg2 * 32);
#pragma unroll
        for (int q2 = 0; q2 < 4; q2++) {
            int byteoff = row * 256 + ((sg2 * 64 + q2 * 16) ^ ((row & 7) << 4));
            dq[q2] = *(const uint4*)((char*)smem + byteoff);
        }
    } else {
        float* ofz = o_f;
        if (EPI == 3)
            ofz = o_f + (size_t)blockIdx.z * (size_t)gridDim.x * 128 * ND;
#pragma unroll
        for (int mi = 0; mi < 4; mi++) {
#pragma unroll
            for (int ni = 0; ni < 2; ni++) {
#pragma unroll
                for (int r = 0; r < 4; r++) {
                    int row = m0 + wr * 64 + mi * 16 + lg * 4 + r;
                    int col = n0 + wc * 32 + ni * 16 + lr;
                    if (EPI == 1) {
                        float c = acc[mi][ni][r] + bias[col];
                        float gg = 0.5f * c * (1.f + erff(c * 0.70710678f));
                        o_bf[(size_t)row * ND + col] = f2bf(gg);
                    } else if (EPI == 2) {
                        float c = acc[mi][ni][r] + bias[col];
                        o_f[(size_t)row * ND + col] = c + res[(size_t)row * ND + col];
                    } else {
                        ofz[(size_t)row * ND + col] = acc[mi][ni][r];
                    }
                }
            }
        }
    }
}

// ---------------- split-K combine for fc2: mout += bias + sum_z partial ----------------
__global__ __launch_bounds__(256)
void combine2_k(const float* __restrict__ fcp, const float* __restrict__ fc2b,
                float* __restrict__ mout)
{
    const int i = blockIdx.x * 256 + threadIdx.x;   // 0..524287
    const int col = i & 511;
    float s = fc2b[col] + fcp[i] + fcp[i + 524288] + fcp[i + 2 * 524288] + fcp[i + 3 * 524288];
    mout[i] += s;
}

// ---------------- flash attention (split-KV partials); K|V packed rows of 1024 ----------------
// h innermost for assign L2 reuse; setprio on MFMA clusters; h==0 blocks also
// accumulate the per-(b,k) assign count partials (replaces the count2 pass).
__global__ __launch_bounds__(256)
void attn_k(const ushort* __restrict__ qbf, const ushort* __restrict__ kv,
            const float* __restrict__ assign,
            float* __restrict__ partO, float* __restrict__ partML,
            float* __restrict__ cpart)
{
    const int h = blockIdx.x, s = blockIdx.y, b = blockIdx.z;
    __shared__ ushort Qs[64 * 64];
    __shared__ ushort Ks[64 * 64];
    __shared__ ushort Vt[64 * 64];
    __shared__ ushort Ps[64 * 64];
    __shared__ float  Lm[64 * 64];
    const int tid = threadIdx.x;
    const int w = tid >> 6, l = tid & 63, lg = l >> 4, lr = l & 15;
    const int rr = tid >> 2, qt = tid & 3;

    { // stage Q once
        const uint4* src = (const uint4*)(qbf + rr * 512 + h * 64 + qt * 16);
        uint4 t0 = src[0], t1 = src[1];
        int kb = qt * 32;
        *(uint4*)((char*)Qs + rr * 128 + ( kb       ^ ((rr & 7) << 4))) = t0;
        *(uint4*)((char*)Qs + rr * 128 + ((kb + 16) ^ ((rr & 7) << 4))) = t1;
    }

    const f32x4 fzero = {0.f, 0.f, 0.f, 0.f};
    f32x4 oacc[4];
#pragma unroll
    for (int ni = 0; ni < 4; ni++) oacc[ni] = fzero;
    float m_run[4], l_run[4];
#pragma unroll
    for (int r = 0; r < 4; r++) { m_run[r] = -3e38f; l_run[r] = 0.f; }
    float csum[16];
#pragma unroll
    for (int i = 0; i < 16; i++) csum[i] = 0.f;

    const int v00 = s * 512;

    for (int c = 0; c < 8; ++c) {
        const int vb = v00 + c * 64;
        __syncthreads();
        {
            const size_t rowb = ((size_t)b * 4096 + vb + rr) * 1024 + h * 64;
            const uint4* srck = (const uint4*)(kv + rowb + qt * 16);
            uint4 k0 = srck[0], k1 = srck[1];
            int kb = qt * 32;
            *(uint4*)((char*)Ks + rr * 128 + ( kb       ^ ((rr & 7) << 4))) = k0;
            *(uint4*)((char*)Ks + rr * 128 + ((kb + 16) ^ ((rr & 7) << 4))) = k1;
            const ushort* srcv = kv + rowb + 512 + qt * 16;
            ushort vvv[16];
            *(uint4*)&vvv[0] = ((const uint4*)srcv)[0];
            *(uint4*)&vvv[8] = ((const uint4*)srcv)[1];
#pragma unroll
            for (int i = 0; i < 16; i++) {
                int dk = qt * 16 + i;
                *(ushort*)((char*)Vt + dk * 128 + ((rr * 2) ^ ((dk & 7) << 4))) = vvv[i];
            }
            const float4* srca = (const float4*)(assign + ((size_t)b * 4096 + vb + rr) * 64 + qt * 16);
            float4 A0 = srca[0], A1 = srca[1], A2 = srca[2], A3 = srca[3];
            float av[16] = {A0.x, A0.y, A0.z, A0.w, A1.x, A1.y, A1.z, A1.w,
                            A2.x, A2.y, A2.z, A2.w, A3.x, A3.y, A3.z, A3.w};
            if (h == 0) {
#pragma unroll
                for (int i = 0; i < 16; i++) csum[i] += av[i];
            }
#pragma unroll
            for (int i = 0; i < 16; i++)
                Lm[(qt * 16 + i) * 64 + rr] = __logf(fminf(fmaxf(av[i], 0.f), 1.f) + 1e-6f);
        }
        __syncthreads();

        f32x4 sacc[4];
#pragma unroll
        for (int ni = 0; ni < 4; ni++) sacc[ni] = fzero;
        __builtin_amdgcn_s_setprio(1);
#pragma unroll
        for (int kk = 0; kk < 2; kk++) {
            int kb = (kk * 32 + lg * 8) * 2;
            int qrow = w * 16 + lr;
            bf16x8 aq = *(bf16x8*)((char*)Qs + qrow * 128 + (kb ^ ((qrow & 7) << 4)));
#pragma unroll
            for (int ni = 0; ni < 4; ni++) {
                int kr = ni * 16 + lr;
                bf16x8 bk = *(bf16x8*)((char*)Ks + kr * 128 + (kb ^ ((kr & 7) << 4)));
                sacc[ni] = __builtin_amdgcn_mfma_f32_16x16x32_bf16(aq, bk, sacc[ni], 0, 0, 0);
            }
        }
        __builtin_amdgcn_s_setprio(0);
        float sv[4][4], mx[4];
#pragma unroll
        for (int r = 0; r < 4; r++) {
            int q = w * 16 + lg * 4 + r;
            float m_ = -3e38f;
#pragma unroll
            for (int ni = 0; ni < 4; ni++) {
                float xx = sacc[ni][r] * 0.125f + Lm[q * 64 + ni * 16 + lr];
                sv[ni][r] = xx;
                m_ = fmaxf(m_, xx);
            }
            mx[r] = m_;
        }
#pragma unroll
        for (int off = 1; off < 16; off <<= 1)
#pragma unroll
            for (int r = 0; r < 4; r++) mx[r] = fmaxf(mx[r], __shfl_xor(mx[r], off, 64));
        float scale[4], lad[4];
#pragma unroll
        for (int r = 0; r < 4; r++) {
            float mn = fmaxf(m_run[r], mx[r]);
            scale[r] = __expf(m_run[r] - mn);
            m_run[r] = mn;
            float ls = 0.f;
#pragma unroll
            for (int ni = 0; ni < 4; ni++) {
                float p = __expf(sv[ni][r] - mn);
                sv[ni][r] = p;
                ls += p;
            }
            lad[r] = ls;
        }
#pragma unroll
        for (int off = 1; off < 16; off <<= 1)
#pragma unroll
            for (int r = 0; r < 4; r++) lad[r] += __shfl_xor(lad[r], off, 64);
#pragma unroll
        for (int r = 0; r < 4; r++) l_run[r] = l_run[r] * scale[r] + lad[r];
#pragma unroll
        for (int ni = 0; ni < 4; ni++) {
            f32x4 o = oacc[ni];
            o[0] *= scale[0]; o[1] *= scale[1]; o[2] *= scale[2]; o[3] *= scale[3];
            oacc[ni] = o;
        }
#pragma unroll
        for (int ni = 0; ni < 4; ni++)
#pragma unroll
            for (int r = 0; r < 4; r++) {
                int q = w * 16 + lg * 4 + r;
                int key = ni * 16 + lr;
                *(ushort*)((char*)Ps + q * 128 + ((key * 2) ^ ((q & 7) << 4))) = f2bf(sv[ni][r]);
            }
        __builtin_amdgcn_s_setprio(1);
#pragma unroll
        for (int kk = 0; kk < 2; kk++) {
            int kb = (kk * 32 + lg * 8) * 2;
            int prow = w * 16 + lr;
            bf16x8 ap = *(bf16x8*)((char*)Ps + prow * 128 + (kb ^ ((prow & 7) << 4)));
#pragma unroll
            for (int ni = 0; ni < 4; ni++) {
                int dk = ni * 16 + lr;
                bf16x8 bv = *(bf16x8*)((char*)Vt + dk * 128 + (kb ^ ((dk & 7) << 4)));
                oacc[ni] = __builtin_amdgcn_mfma_f32_16x16x32_bf16(ap, bv, oacc[ni], 0, 0, 0);
            }
        }
        __builtin_amdgcn_s_setprio(0);
    }
    const size_t ob = ((size_t)((b * 8 + h) * 8 + s)) * 4096;
#pragma unroll
    for (int ni = 0; ni < 4; ni++)
#pragma unroll
        for (int r = 0; r < 4; r++) {
            int q = w * 16 + lg * 4 + r;
            int dk = ni * 16 + lr;
            partO[ob + q * 64 + dk] = oacc[ni][r];
        }
    if (lr == 0) {
#pragma unroll
        for (int r = 0; r < 4; r++) {
            int q = w * 16 + lg * 4 + r;
            partML[((b * 8 + h) * 8 + s) * 128 + q * 2 + 0] = m_run[r];
            partML[((b * 8 + h) * 8 + s) * 128 + q * 2 + 1] = l_run[r];
        }
    }
    // count partials: h==0 blocks reduce csum over the 64 v-rows (Lm reused as scratch)
    if (h == 0) {
        __syncthreads();
#pragma unroll
        for (int i = 0; i < 16; i++)
            Lm[rr * 64 + qt * 16 + i] = csum[i];
        __syncthreads();
        if (tid < 64) {
            float ssum = 0.f;
            for (int r2 = 0; r2 < 64; r2++) ssum += Lm[r2 * 64 + tid];
            cpart[((size_t)b * 64 + tid) * 8 + s] = ssum;
        }
    }
}

// ---------------- merge split-KV partials, empty-slot fallback ----------------
__global__ __launch_bounds__(256)
void combine_k(const float* __restrict__ partO, const float* __restrict__ partML,
               const float* __restrict__ cls, const float* __restrict__ cnt,
               float* __restrict__ mout)
{
    const int bh = blockIdx.x, b = bh >> 3, h = bh & 7;
    __shared__ float Ms[64], Ls[64];
    const int tid = threadIdx.x;
    if (tid < 64) {
        float M = -3e38f;
#pragma unroll
        for (int s2 = 0; s2 < 8; s2++) M = fmaxf(M, partML[(bh * 8 + s2) * 128 + tid * 2]);
        float L = 0.f;
#pragma unroll
        for (int s2 = 0; s2 < 8; s2++) {
            float m_ = partML[(bh * 8 + s2) * 128 + tid * 2];
            float l_ = partML[(bh * 8 + s2) * 128 + tid * 2 + 1];
            L += l_ * __expf(m_ - M);
        }
        Ms[tid] = M; Ls[tid] = L;
    }
    __syncthreads();
#pragma unroll
    for (int i = 0; i < 16; i++) {
        int e = i * 256 + tid;
        int q = e >> 6, dk = e & 63;
        float o = 0.f;
#pragma unroll
        for (int s2 = 0; s2 < 8; s2++) {
            float m_ = partML[(bh * 8 + s2) * 128 + q * 2];
            o += partO[(size_t)(bh * 8 + s2) * 4096 + e] * __expf(m_ - Ms[q]);
        }
        float val = o / (Ls[q] + 1e-8f);
        if (cnt[b * 64 + q] <= 1e-6f) val = cls[q * 512 + h * 64 + dk];
        mout[((size_t)b * 64 + q) * 512 + h * 64 + dk] = val;
    }
}

// ---------------- LN over rows of m (pre-FFN) ----------------
__global__ __launch_bounds__(256)
void ln_rows_k(const float* __restrict__ m, const float* __restrict__ g,
               const float* __restrict__ be, ushort* __restrict__ out)
{
    const int r = blockIdx.x, tid = threadIdx.x;
    float v0 = m[(size_t)r * 512 + tid];
    float v1 = m[(size_t)r * 512 + tid + 256];
    __shared__ float2 red[256];
    float2 sr = block_reduce2(v0 + v1, v0 * v0 + v1 * v1, red, tid);
    float mu = sr.x * (1.f / 512.f);
    float var = sr.y * (1.f / 512.f) - mu * mu;
    float inv = rsqrtf(var + 1e-5f);
    out[(size_t)r * 512 + tid]       = f2bf((v0 - mu) * inv * g[tid] + be[tid]);
    out[(size_t)r * 512 + tid + 256] = f2bf((v1 - mu) * inv * g[tid + 256] + be[tid + 256]);
}

extern "C" void kernel_launch(void* const* d_in, const int* in_sizes, int n_in,
                              void* d_out, int out_size, void* d_ws, size_t ws_size,
                              hipStream_t stream)
{
    const float* x      = (const float*)d_in[0];
    const float* assign = (const float*)d_in[1];
    const float* E      = (const float*)d_in[2];
    const float* cls0   = (const float*)d_in[3];
    const float* e2dw   = (const float*)d_in[4];
    const float* e2db   = (const float*)d_in[5];
    const float* wq     = (const float*)d_in[6];
    const float* wqb    = (const float*)d_in[7];
    const float* wk     = (const float*)d_in[8];
    const float* wkb    = (const float*)d_in[9];
    const float* wv     = (const float*)d_in[10];
    const float* wvb    = (const float*)d_in[11];
    const float* lng    = (const float*)d_in[12];
    const float* lnbv   = (const float*)d_in[13];
    const float* fc1w   = (const float*)d_in[14];
    const float* fc1b   = (const float*)d_in[15];
    const float* fc2w   = (const float*)d_in[16];
    const float* fc2b   = (const float*)d_in[17];

    float* mout = (float*)d_out;
    float* cnt  = mout + (size_t)16 * 64 * 512;
    float* emp  = cnt + 16 * 64;

    char* ws = (char*)d_ws;
    size_t off = 0;
    auto alloc = [&](size_t bytes) -> char* {
        char* p = ws + off;
        off = (off + bytes + 255) & ~(size_t)255;
        return p;
    };
    float*  cls    = (float*) alloc((size_t)64 * 512 * 4);
    ushort* clsln  = (ushort*)alloc((size_t)64 * 512 * 2);
    ushort* qbf    = (ushort*)alloc((size_t)64 * 512 * 2);
    ushort* wkvt   = (ushort*)alloc((size_t)1024 * 512 * 2);
    float*  biaskv = (float*) alloc((size_t)1024 * 4);
    ushort* fc1t   = (ushort*)alloc((size_t)2048 * 512 * 2);
    ushort* fc2t   = (ushort*)alloc((size_t)512 * 2048 * 2);
    ushort* kvb    = (ushort*)alloc((size_t)16 * 4096 * 1024 * 2);
    float*  partO  = (float*) alloc((size_t)16 * 8 * 8 * 64 * 64 * 4);
    float*  partML = (float*) alloc((size_t)16 * 8 * 8 * 64 * 2 * 4);
    float*  cpart  = (float*) alloc((size_t)1024 * 8 * 4);
    ushort* lnbf   = (ushort*)alloc((size_t)1024 * 512 * 2);
    ushort* hhb    = (ushort*)alloc((size_t)1024 * 2048 * 2);
    float*  fcp    = (float*) alloc((size_t)4 * 1024 * 512 * 4);
    ushort* xb     = (ushort*)alloc((size_t)16 * 4096 * 512 * 2);
    const bool use_xb = (off <= ws_size);

    prep_cls_k<<<64, 256, 0, stream>>>(E, cls0, e2dw, e2db, lng, lnbv, cls, clsln);
    prep_q_k<<<16, 512, 0, stream>>>(clsln, wq, wqb, qbf);
    wprep_k<<<2564, 256, 0, stream>>>(wk, wv, fc1w, fc2w, wkb, wvb,
                                      wkvt, fc1t, fc2t, biaskv);

    if (use_xb) {
        xcast_k<<<16384, 256, 0, stream>>>(x, xb);
        gemm_k<0, 0, 1, 1024, 512, 512><<<4096, 512, 0, stream>>>(xb, wkvt, biaskv,
                                                                  kvb, nullptr, nullptr);
    } else {
        gemm_k<1, 0, 1, 1024, 512, 512><<<4096, 512, 0, stream>>>(x, wkvt, biaskv,
                                                                  kvb, nullptr, nullptr);
    }
    attn_k<<<dim3(8, 8, 16), 256, 0, stream>>>(qbf, kvb, assign, partO, partML, cpart);
    count_fin_k<<<4, 256, 0, stream>>>(cpart, cnt, emp);
    combine_k<<<128, 256, 0, stream>>>(partO, partML, cls, cnt, mout);
    ln_rows_k<<<1024, 256, 0, stream>>>(mout, lng, lnbv, lnbf);
    gemm_k<0, 1, 0, 2048, 512, 512><<<dim3(8, 16), 512, 0, stream>>>(lnbf, fc1t, fc1b,
                                                                     hhb, nullptr, nullptr);
    gemm_k<0, 3, 0, 512, 512, 2048><<<dim3(8, 4, 4), 512, 0, stream>>>(hhb, fc2t, fc2b,
                                                                       nullptr, nullptr, fcp);
    combine2_k<<<2048, 256, 0, stream>>>(fcp, fc2b, mout);
}

// Round 16
// 289.382 us; speedup vs baseline: 1.0205x; 1.0205x over previous
//
#include <hip/hip_runtime.h>
#include <hip/hip_bf16.h>
#include <cstdint>
#include <cmath>

#define DEV static __device__ __forceinline__

typedef __attribute__((ext_vector_type(8))) short bf16x8;
typedef __attribute__((ext_vector_type(4))) float f32x4;

DEV ushort f2bf(float f) {
    union { float f; uint32_t u; } v; v.f = f;
    uint32_t r = v.u + 0x7FFFu + ((v.u >> 16) & 1u);
    return (ushort)(r >> 16);
}
DEV uint32_t pack2bf(float lo, float hi) {
    return (uint32_t)f2bf(lo) | ((uint32_t)f2bf(hi) << 16);
}
DEV float bf2f(ushort h) {
    union { uint32_t u; float f; } v; v.u = ((uint32_t)h) << 16;
    return v.f;
}
// async global->LDS, 16B per lane; LDS dest = wave-uniform base + lane*16
DEV void gld16(const ushort* g, ushort* l) {
    __builtin_amdgcn_global_load_lds(
        (const __attribute__((address_space(1))) unsigned int*)g,
        (__attribute__((address_space(3))) unsigned int*)l, 16, 0, 0);
}

DEV float2 block_reduce2(float a, float b, float2* red, int tid) {
    red[tid] = make_float2(a, b);
    __syncthreads();
    for (int s2 = 128; s2 > 0; s2 >>= 1) {
        if (tid < s2) {
            float2 o = red[tid + s2];
            float2 m = red[tid];
            red[tid] = make_float2(m.x + o.x, m.y + o.y);
        }
        __syncthreads();
    }
    float2 r = red[0];
    __syncthreads();
    return r;
}

// ---------------- x f32 -> bf16 cast (coalesced, 8 elems/thread) ----------------
__global__ __launch_bounds__(256)
void xcast_k(const float* __restrict__ x, ushort* __restrict__ xb)
{
    const size_t i = (size_t)blockIdx.x * 256 + threadIdx.x;
    const float4* s = (const float4*)(x + i * 8);
    float4 a = s[0], b = s[1];
    uint4 o;
    o.x = pack2bf(a.x, a.y); o.y = pack2bf(a.z, a.w);
    o.z = pack2bf(b.x, b.y); o.w = pack2bf(b.z, b.w);
    *(uint4*)(xb + i * 8) = o;
}

// ---------------- prep: cls = cls0 + E@E2D_w + E2D_b ; clsln = LN(cls) ----------------
__global__ __launch_bounds__(256)
void prep_cls_k(const float* __restrict__ E, const float* __restrict__ cls0,
                const float* __restrict__ w, const float* __restrict__ bb,
                const float* __restrict__ g, const float* __restrict__ be,
                float* __restrict__ cls, ushort* __restrict__ clsln)
{
    const int k = blockIdx.x, tid = threadIdx.x;
    __shared__ float Ek[16];
    if (tid < 16) Ek[tid] = E[k * 16 + tid];
    __syncthreads();
    float vals[2];
#pragma unroll
    for (int j = 0; j < 2; j++) {
        int d = tid + j * 256;
        float a = cls0[k * 512 + d] + bb[d];
#pragma unroll
        for (int e = 0; e < 16; e++) a += Ek[e] * w[e * 512 + d];
        vals[j] = a;
        cls[k * 512 + d] = a;
    }
    __shared__ float2 red[256];
    float2 sr = block_reduce2(vals[0] + vals[1], vals[0] * vals[0] + vals[1] * vals[1], red, tid);
    float mu = sr.x * (1.f / 512.f);
    float var = sr.y * (1.f / 512.f) - mu * mu;
    float inv = rsqrtf(var + 1e-5f);
#pragma unroll
    for (int j = 0; j < 2; j++) {
        int d = tid + j * 256;
        clsln[k * 512 + d] = f2bf((vals[j] - mu) * inv * g[d] + be[d]);
    }
}

// ---------------- prep: q = clsln @ Wq + b (64x512x512, tiny) ----------------
__global__ __launch_bounds__(512)
void prep_q_k(const ushort* __restrict__ clsln, const float* __restrict__ wq,
              const float* __restrict__ wqb, ushort* __restrict__ qbf)
{
    const int kb = blockIdx.x * 4;
    const int n = threadIdx.x;
    __shared__ float Ar[4][512];
#pragma unroll
    for (int j = 0; j < 4; j++) Ar[j][n] = bf2f(clsln[(kb + j) * 512 + n]);
    __syncthreads();
    float acc[4] = {0.f, 0.f, 0.f, 0.f};
    for (int d = 0; d < 512; ++d) {
        float wv = wq[d * 512 + n];
#pragma unroll
        for (int j = 0; j < 4; j++) acc[j] += Ar[j][d] * wv;
    }
#pragma unroll
    for (int j = 0; j < 4; j++) qbf[(kb + j) * 512 + n] = f2bf(acc[j] + wqb[n]);
}

// ---------------- batched weight prep: 4 transposes + bias pack in ONE launch ----------------
__global__ __launch_bounds__(256)
void wprep_k(const float* __restrict__ wk, const float* __restrict__ wv,
             const float* __restrict__ fc1w, const float* __restrict__ fc2w,
             const float* __restrict__ kb, const float* __restrict__ vb,
             ushort* __restrict__ wkvt, ushort* __restrict__ fc1t,
             ushort* __restrict__ fc2t, float* __restrict__ biaskv)
{
    const int id = blockIdx.x;
    if (id >= 2560) {
        int i = (id - 2560) * 256 + threadIdx.x;
        biaskv[i] = (i < 512) ? kb[i] : vb[i - 512];
        return;
    }
    const float* in; ushort* out; int R, C, bx, by;
    if (id < 256)        { in = wk;   out = wkvt;                  R = 512;  C = 512;  int t = id;        bx = t & 15; by = t >> 4; }
    else if (id < 512)   { in = wv;   out = wkvt + 512 * 512;      R = 512;  C = 512;  int t = id - 256;  bx = t & 15; by = t >> 4; }
    else if (id < 1536)  { in = fc1w; out = fc1t;                  R = 512;  C = 2048; int t = id - 512;  bx = t & 63; by = t >> 6; }
    else                 { in = fc2w; out = fc2t;                  R = 2048; C = 512;  int t = id - 1536; bx = t & 15; by = t >> 4; }
    __shared__ float T[32][33];
    const int c0 = bx * 32, r0 = by * 32;
    const int tx = threadIdx.x & 31, ty = threadIdx.x >> 5;
#pragma unroll
    for (int i = 0; i < 32; i += 8)
        T[ty + i][tx] = in[(size_t)(r0 + ty + i) * C + c0 + tx];
    __syncthreads();
#pragma unroll
    for (int i = 0; i < 32; i += 8)
        out[(size_t)(c0 + ty + i) * R + r0 + tx] = f2bf(T[tx][ty + i]);
}

// ---------------- per-tile count partials (transpose in LDS, sum over v) ----------------
__global__ __launch_bounds__(256)
void count2_k(const float* __restrict__ assign, float* __restrict__ partial)
{
    const int vt = blockIdx.x, b = blockIdx.y;
    __shared__ float T[64][65];
    const int rr = threadIdx.x >> 2, sg = threadIdx.x & 3;
    const float4* src = (const float4*)(assign + ((size_t)b * 4096 + vt * 64 + rr) * 64 + sg * 16);
    float4 a0 = src[0], a1 = src[1], a2 = src[2], a3 = src[3];
    float* tr = &T[rr][sg * 16];
    tr[0] = a0.x; tr[1] = a0.y; tr[2] = a0.z; tr[3] = a0.w;
    tr[4] = a1.x; tr[5] = a1.y; tr[6] = a1.z; tr[7] = a1.w;
    tr[8] = a2.x; tr[9] = a2.y; tr[10] = a2.z; tr[11] = a2.w;
    tr[12] = a3.x; tr[13] = a3.y; tr[14] = a3.z; tr[15] = a3.w;
    __syncthreads();
    const int k = rr;
    float ssum = 0.f;
#pragma unroll
    for (int j = 0; j < 4; j++)
#pragma unroll
        for (int t2 = 0; t2 < 4; t2++) ssum += T[sg * 16 + j * 4 + t2][k];
    ssum += __shfl_xor(ssum, 1, 64);
    ssum += __shfl_xor(ssum, 2, 64);
    if (sg == 0) partial[((size_t)b * 64 + k) * 64 + vt] = ssum;
}

// ---------------- 128x128xBK64 bf16 MFMA GEMM, 8 waves (512 thr), single-buffer ----------------
// (r12-best configuration)
template<int AMODE, int EPI, int SWZ, int ND, int KD, int LDK>
__global__ __launch_bounds__(512)
void gemm_k(const void* __restrict__ Ap, const ushort* __restrict__ Bt,
            const float* __restrict__ bias,
            ushort* __restrict__ o_bf, const float* __restrict__ res,
            float* __restrict__ o_f)
{
    __shared__ ushort smem[16384];
    ushort* As = smem;
    ushort* Bs = smem + 8192;
    int m0, n0;
    if (SWZ) {
        int L = blockIdx.x;
        int c = L & 7, j = L >> 3;
        m0 = (c * 64 + (j >> 3)) * 128;
        n0 = (j & 7) * 128;
    } else {
        m0 = blockIdx.x * 128;
        n0 = blockIdx.y * 128;
    }
    const int tid = threadIdx.x;
    const int w = tid >> 6, l = tid & 63;
    const int wr = w >> 2, wc = w & 3;
    const int lg = l >> 4, lr = l & 15;

    const f32x4 fzero = {0.f, 0.f, 0.f, 0.f};
    f32x4 acc[4][2];
#pragma unroll
    for (int i = 0; i < 4; i++)
#pragma unroll
        for (int j = 0; j < 2; j++) acc[i][j] = fzero;

    const int lrow8 = l >> 3;
    const int colswz = ((l & 7) ^ lrow8) * 8;
    const ushort* gB  = Bt + (size_t)(n0 + w * 16 + lrow8) * LDK + colswz;
    const ushort* gA0 = (const ushort*)Ap + (size_t)(m0 + w * 16 + lrow8) * LDK + colswz;
    const float*  gA1 = (const float*)Ap + (size_t)(m0 + w * 16 + (l >> 2)) * LDK + (l & 3) * 16;

    const int kbase = blockIdx.z * KD;
    constexpr int NT = KD / 64;
#pragma unroll
    for (int t = 0; t < NT; ++t) {
        const int kt = kbase + t * 64;
        __syncthreads();
        if (AMODE == 0) {
#pragma unroll
            for (int i = 0; i < 2; i++) {
                gld16(gA0 + (size_t)i * 8 * LDK + kt, As + (w * 16 + i * 8) * 64);
                gld16(gB + (size_t)i * 8 * LDK + kt, Bs + (w * 16 + i * 8) * 64);
            }
        } else {
            float4 av[4];
#pragma unroll
            for (int i = 0; i < 4; i++)
                av[i] = *(const float4*)(gA1 + kt + i * 4);
#pragma unroll
            for (int i = 0; i < 2; i++)
                gld16(gB + (size_t)i * 8 * LDK + kt, Bs + (w * 16 + i * 8) * 64);
            {
                int r = w * 16 + (l >> 2);
                uint2 p0, p1;
                p0.x = pack2bf(av[0].x, av[0].y); p0.y = pack2bf(av[0].z, av[0].w);
                uint2 q0; q0.x = pack2bf(av[1].x, av[1].y); q0.y = pack2bf(av[1].z, av[1].w);
                p1.x = pack2bf(av[2].x, av[2].y); p1.y = pack2bf(av[2].z, av[2].w);
                uint2 q1; q1.x = pack2bf(av[3].x, av[3].y); q1.y = pack2bf(av[3].z, av[3].w);
                int cb = (l & 3) * 32;
                *(uint2*)((char*)As + r * 128 + ((cb     ) ^ ((r & 7) << 4))) = p0;
                *(uint2*)((char*)As + r * 128 + ((cb +  8) ^ ((r & 7) << 4))) = q0;
                *(uint2*)((char*)As + r * 128 + ((cb + 16) ^ ((r & 7) << 4))) = p1;
                *(uint2*)((char*)As + r * 128 + ((cb + 24) ^ ((r & 7) << 4))) = q1;
            }
        }
        asm volatile("s_waitcnt vmcnt(0)" ::: "memory");
        __syncthreads();
#pragma unroll
        for (int kk = 0; kk < 2; kk++) {
            int kb = (kk * 32 + lg * 8) * 2;
            bf16x8 af[4], bfv[2];
#pragma unroll
            for (int mi = 0; mi < 4; mi++) {
                int row = wr * 64 + mi * 16 + lr;
                af[mi] = *(bf16x8*)((char*)As + row * 128 + (kb ^ ((row & 7) << 4)));
            }
#pragma unroll
            for (int ni = 0; ni < 2; ni++) {
                int row = wc * 32 + ni * 16 + lr;
                bfv[ni] = *(bf16x8*)((char*)Bs + row * 128 + (kb ^ ((row & 7) << 4)));
            }
#pragma unroll
            for (int mi = 0; mi < 4; mi++)
#pragma unroll
                for (int ni = 0; ni < 2; ni++)
                    acc[mi][ni] = __builtin_amdgcn_mfma_f32_16x16x32_bf16(af[mi], bfv[ni], acc[mi][ni], 0, 0, 0);
        }
    }

    if (EPI == 0) {
        __syncthreads();
#pragma unroll
        for (int mi = 0; mi < 4; mi++)
#pragma unroll
            for (int ni = 0; ni < 2; ni++)
#pragma unroll
                for (int r = 0; r < 4; r++) {
                    int rl = wr * 64 + mi * 16 + lg * 4 + r;
                    int cl = wc * 32 + ni * 16 + lr;
                    int byteoff = rl * 256 + ((cl * 2) ^ ((rl & 7) << 4));
                    *(ushort*)((char*)smem + byteoff) = f2bf(acc[mi][ni][r] + bias[n0 + cl]);
                }
        __syncthreads();
        const int row = tid >> 2, sg2 = tid & 3;
        uint4* dq = (uint4*)(o_bf + (size_t)(m0 + row) * ND + n0 + sg2 * 32);
#pragma unroll
        for (int q2 = 0; q2 < 4; q2++) {
            int byteoff = row * 256 + ((sg2 * 64 + q2 * 16) ^ ((row & 7) << 4));
            dq[q2] = *(const uint4*)((char*)smem + byteoff);
        }
    } else {
        float* ofz = o_f;
        if (EPI == 3)
            ofz = o_f + (size_t)blockIdx.z * (size_t)gridDim.x * 128 * ND;
#pragma unroll
        for (int mi = 0; mi < 4; mi++) {
#pragma unroll
            for (int ni = 0; ni < 2; ni++) {
#pragma unroll
                for (int r = 0; r < 4; r++) {
                    int row = m0 + wr * 64 + mi * 16 + lg * 4 + r;
                    int col = n0 + wc * 32 + ni * 16 + lr;
                    if (EPI == 1) {
                        float c = acc[mi][ni][r] + bias[col];
                        float gg = 0.5f * c * (1.f + erff(c * 0.70710678f));
                        o_bf[(size_t)row * ND + col] = f2bf(gg);
                    } else if (EPI == 2) {
                        float c = acc[mi][ni][r] + bias[col];
                        o_f[(size_t)row * ND + col] = c + res[(size_t)row * ND + col];
                    } else {
                        ofz[(size_t)row * ND + col] = acc[mi][ni][r];
                    }
                }
            }
        }
    }
}

// ---------------- split-K combine for fc2: mout += bias + sum_z partial ----------------
__global__ __launch_bounds__(256)
void combine2_k(const float* __restrict__ fcp, const float* __restrict__ fc2b,
                float* __restrict__ mout)
{
    const int i = blockIdx.x * 256 + threadIdx.x;   // 0..524287
    const int col = i & 511;
    float s = fc2b[col] + fcp[i] + fcp[i + 524288] + fcp[i + 2 * 524288] + fcp[i + 3 * 524288];
    mout[i] += s;
}

// ---------------- flash attention (split-KV partials); K|V packed rows of 1024 ----------------
// h innermost for assign L2 reuse; setprio on MFMA clusters (r14-best config).
__global__ __launch_bounds__(256)
void attn_k(const ushort* __restrict__ qbf, const ushort* __restrict__ kv,
            const float* __restrict__ assign,
            float* __restrict__ partO, float* __restrict__ partML)
{
    const int h = blockIdx.x, s = blockIdx.y, b = blockIdx.z;
    __shared__ ushort Qs[64 * 64];
    __shared__ ushort Ks[64 * 64];
    __shared__ ushort Vt[64 * 64];
    __shared__ ushort Ps[64 * 64];
    __shared__ float  Lm[64 * 64];
    const int tid = threadIdx.x;
    const int w = tid >> 6, l = tid & 63, lg = l >> 4, lr = l & 15;
    const int rr = tid >> 2, qt = tid & 3;

    { // stage Q once
        const uint4* src = (const uint4*)(qbf + rr * 512 + h * 64 + qt * 16);
        uint4 t0 = src[0], t1 = src[1];
        int kb = qt * 32;
        *(uint4*)((char*)Qs + rr * 128 + ( kb       ^ ((rr & 7) << 4))) = t0;
        *(uint4*)((char*)Qs + rr * 128 + ((kb + 16) ^ ((rr & 7) << 4))) = t1;
    }

    const f32x4 fzero = {0.f, 0.f, 0.f, 0.f};
    f32x4 oacc[4];
#pragma unroll
    for (int ni = 0; ni < 4; ni++) oacc[ni] = fzero;
    float m_run[4], l_run[4];
#pragma unroll
    for (int r = 0; r < 4; r++) { m_run[r] = -3e38f; l_run[r] = 0.f; }

    const int v00 = s * 512;

    for (int c = 0; c < 8; ++c) {
        const int vb = v00 + c * 64;
        __syncthreads();
        {
            const size_t rowb = ((size_t)b * 4096 + vb + rr) * 1024 + h * 64;
            const uint4* srck = (const uint4*)(kv + rowb + qt * 16);
            uint4 k0 = srck[0], k1 = srck[1];
            int kb = qt * 32;
            *(uint4*)((char*)Ks + rr * 128 + ( kb       ^ ((rr & 7) << 4))) = k0;
            *(uint4*)((char*)Ks + rr * 128 + ((kb + 16) ^ ((rr & 7) << 4))) = k1;
            const ushort* srcv = kv + rowb + 512 + qt * 16;
            ushort vvv[16];
            *(uint4*)&vvv[0] = ((const uint4*)srcv)[0];
            *(uint4*)&vvv[8] = ((const uint4*)srcv)[1];
#pragma unroll
            for (int i = 0; i < 16; i++) {
                int dk = qt * 16 + i;
                *(ushort*)((char*)Vt + dk * 128 + ((rr * 2) ^ ((dk & 7) << 4))) = vvv[i];
            }
            const float4* srca = (const float4*)(assign + ((size_t)b * 4096 + vb + rr) * 64 + qt * 16);
            float4 A0 = srca[0], A1 = srca[1], A2 = srca[2], A3 = srca[3];
            float av[16] = {A0.x, A0.y, A0.z, A0.w, A1.x, A1.y, A1.z, A1.w,
                            A2.x, A2.y, A2.z, A2.w, A3.x, A3.y, A3.z, A3.w};
#pragma unroll
            for (int i = 0; i < 16; i++)
                Lm[(qt * 16 + i) * 64 + rr] = __logf(fminf(fmaxf(av[i], 0.f), 1.f) + 1e-6f);
        }
        __syncthreads();

        f32x4 sacc[4];
#pragma unroll
        for (int ni = 0; ni < 4; ni++) sacc[ni] = fzero;
        __builtin_amdgcn_s_setprio(1);
#pragma unroll
        for (int kk = 0; kk < 2; kk++) {
            int kb = (kk * 32 + lg * 8) * 2;
            int qrow = w * 16 + lr;
            bf16x8 aq = *(bf16x8*)((char*)Qs + qrow * 128 + (kb ^ ((qrow & 7) << 4)));
#pragma unroll
            for (int ni = 0; ni < 4; ni++) {
                int kr = ni * 16 + lr;
                bf16x8 bk = *(bf16x8*)((char*)Ks + kr * 128 + (kb ^ ((kr & 7) << 4)));
                sacc[ni] = __builtin_amdgcn_mfma_f32_16x16x32_bf16(aq, bk, sacc[ni], 0, 0, 0);
            }
        }
        __builtin_amdgcn_s_setprio(0);
        float sv[4][4], mx[4];
#pragma unroll
        for (int r = 0; r < 4; r++) {
            int q = w * 16 + lg * 4 + r;
            float m_ = -3e38f;
#pragma unroll
            for (int ni = 0; ni < 4; ni++) {
                float xx = sacc[ni][r] * 0.125f + Lm[q * 64 + ni * 16 + lr];
                sv[ni][r] = xx;
                m_ = fmaxf(m_, xx);
            }
            mx[r] = m_;
        }
#pragma unroll
        for (int off = 1; off < 16; off <<= 1)
#pragma unroll
            for (int r = 0; r < 4; r++) mx[r] = fmaxf(mx[r], __shfl_xor(mx[r], off, 64));
        float scale[4], lad[4];
#pragma unroll
        for (int r = 0; r < 4; r++) {
            float mn = fmaxf(m_run[r], mx[r]);
            scale[r] = __expf(m_run[r] - mn);
            m_run[r] = mn;
            float ls = 0.f;
#pragma unroll
            for (int ni = 0; ni < 4; ni++) {
                float p = __expf(sv[ni][r] - mn);
                sv[ni][r] = p;
                ls += p;
            }
            lad[r] = ls;
        }
#pragma unroll
        for (int off = 1; off < 16; off <<= 1)
#pragma unroll
            for (int r = 0; r < 4; r++) lad[r] += __shfl_xor(lad[r], off, 64);
#pragma unroll
        for (int r = 0; r < 4; r++) l_run[r] = l_run[r] * scale[r] + lad[r];
#pragma unroll
        for (int ni = 0; ni < 4; ni++) {
            f32x4 o = oacc[ni];
            o[0] *= scale[0]; o[1] *= scale[1]; o[2] *= scale[2]; o[3] *= scale[3];
            oacc[ni] = o;
        }
#pragma unroll
        for (int ni = 0; ni < 4; ni++)
#pragma unroll
            for (int r = 0; r < 4; r++) {
                int q = w * 16 + lg * 4 + r;
                int key = ni * 16 + lr;
                *(ushort*)((char*)Ps + q * 128 + ((key * 2) ^ ((q & 7) << 4))) = f2bf(sv[ni][r]);
            }
        __builtin_amdgcn_s_setprio(1);
#pragma unroll
        for (int kk = 0; kk < 2; kk++) {
            int kb = (kk * 32 + lg * 8) * 2;
            int prow = w * 16 + lr;
            bf16x8 ap = *(bf16x8*)((char*)Ps + prow * 128 + (kb ^ ((prow & 7) << 4)));
#pragma unroll
            for (int ni = 0; ni < 4; ni++) {
                int dk = ni * 16 + lr;
                bf16x8 bv = *(bf16x8*)((char*)Vt + dk * 128 + (kb ^ ((dk & 7) << 4)));
                oacc[ni] = __builtin_amdgcn_mfma_f32_16x16x32_bf16(ap, bv, oacc[ni], 0, 0, 0);
            }
        }
        __builtin_amdgcn_s_setprio(0);
    }
    const size_t ob = ((size_t)((b * 8 + h) * 8 + s)) * 4096;
#pragma unroll
    for (int ni = 0; ni < 4; ni++)
#pragma unroll
        for (int r = 0; r < 4; r++) {
            int q = w * 16 + lg * 4 + r;
            int dk = ni * 16 + lr;
            partO[ob + q * 64 + dk] = oacc[ni][r];
        }
    if (lr == 0) {
#pragma unroll
        for (int r = 0; r < 4; r++) {
            int q = w * 16 + lg * 4 + r;
            partML[((b * 8 + h) * 8 + s) * 128 + q * 2 + 0] = m_run[r];
            partML[((b * 8 + h) * 8 + s) * 128 + q * 2 + 1] = l_run[r];
        }
    }
}

// ---------------- merge split-KV partials, empty-slot fallback; also finalizes counts ----------------
// cnt computed locally from cpart (64 partials per (b,q)); h==0 block writes cnt/emp.
__global__ __launch_bounds__(256)
void combine_k(const float* __restrict__ partO, const float* __restrict__ partML,
               const float* __restrict__ cls, const float* __restrict__ cpart,
               float* __restrict__ cnt, float* __restrict__ emp,
               float* __restrict__ mout)
{
    const int bh = blockIdx.x, b = bh >> 3, h = bh & 7;
    __shared__ float Ms[64], Ls[64], Cs[64];
    const int tid = threadIdx.x;
    if (tid < 64) {
        float M = -3e38f;
#pragma unroll
        for (int s2 = 0; s2 < 8; s2++) M = fmaxf(M, partML[(bh * 8 + s2) * 128 + tid * 2]);
        float L = 0.f;
#pragma unroll
        for (int s2 = 0; s2 < 8; s2++) {
            float m_ = partML[(bh * 8 + s2) * 128 + tid * 2];
            float l_ = partML[(bh * 8 + s2) * 128 + tid * 2 + 1];
            L += l_ * __expf(m_ - M);
        }
        Ms[tid] = M; Ls[tid] = L;
        // count: sum the 64 v-tile partials for (b, k=tid)
        const float4* p = (const float4*)(cpart + ((size_t)b * 64 + tid) * 64);
        float cs = 0.f;
#pragma unroll
        for (int t = 0; t < 16; t++) {
            float4 f = p[t];
            cs += f.x + f.y + f.z + f.w;
        }
        Cs[tid] = cs;
        if (h == 0) {
            cnt[b * 64 + tid] = cs;
            emp[b * 64 + tid] = (cs <= 1e-6f) ? 1.f : 0.f;
        }
    }
    __syncthreads();
#pragma unroll
    for (int i = 0; i < 16; i++) {
        int e = i * 256 + tid;
        int q = e >> 6, dk = e & 63;
        float o = 0.f;
#pragma unroll
        for (int s2 = 0; s2 < 8; s2++) {
            float m_ = partML[(bh * 8 + s2) * 128 + q * 2];
            o += partO[(size_t)(bh * 8 + s2) * 4096 + e] * __expf(m_ - Ms[q]);
        }
        float val = o / (Ls[q] + 1e-8f);
        if (Cs[q] <= 1e-6f) val = cls[q * 512 + h * 64 + dk];
        mout[((size_t)b * 64 + q) * 512 + h * 64 + dk] = val;
    }
}

// ---------------- LN over rows of m (pre-FFN) ----------------
__global__ __launch_bounds__(256)
void ln_rows_k(const float* __restrict__ m, const float* __restrict__ g,
               const float* __restrict__ be, ushort* __restrict__ out)
{
    const int r = blockIdx.x, tid = threadIdx.x;
    float v0 = m[(size_t)r * 512 + tid];
    float v1 = m[(size_t)r * 512 + tid + 256];
    __shared__ float2 red[256];
    float2 sr = block_reduce2(v0 + v1, v0 * v0 + v1 * v1, red, tid);
    float mu = sr.x * (1.f / 512.f);
    float var = sr.y * (1.f / 512.f) - mu * mu;
    float inv = rsqrtf(var + 1e-5f);
    out[(size_t)r * 512 + tid]       = f2bf((v0 - mu) * inv * g[tid] + be[tid]);
    out[(size_t)r * 512 + tid + 256] = f2bf((v1 - mu) * inv * g[tid + 256] + be[tid + 256]);
}

extern "C" void kernel_launch(void* const* d_in, const int* in_sizes, int n_in,
                              void* d_out, int out_size, void* d_ws, size_t ws_size,
                              hipStream_t stream)
{
    const float* x      = (const float*)d_in[0];
    const float* assign = (const float*)d_in[1];
    const float* E      = (const float*)d_in[2];
    const float* cls0   = (const float*)d_in[3];
    const float* e2dw   = (const float*)d_in[4];
    const float* e2db   = (const float*)d_in[5];
    const float* wq     = (const float*)d_in[6];
    const float* wqb    = (const float*)d_in[7];
    const float* wk     = (const float*)d_in[8];
    const float* wkb    = (const float*)d_in[9];
    const float* wv     = (const float*)d_in[10];
    const float* wvb    = (const float*)d_in[11];
    const float* lng    = (const float*)d_in[12];
    const float* lnbv   = (const float*)d_in[13];
    const float* fc1w   = (const float*)d_in[14];
    const float* fc1b   = (const float*)d_in[15];
    const float* fc2w   = (const float*)d_in[16];
    const float* fc2b   = (const float*)d_in[17];

    float* mout = (float*)d_out;
    float* cnt  = mout + (size_t)16 * 64 * 512;
    float* emp  = cnt + 16 * 64;

    char* ws = (char*)d_ws;
    size_t off = 0;
    auto alloc = [&](size_t bytes) -> char* {
        char* p = ws + off;
        off = (off + bytes + 255) & ~(size_t)255;
        return p;
    };
    float*  cls    = (float*) alloc((size_t)64 * 512 * 4);
    ushort* clsln  = (ushort*)alloc((size_t)64 * 512 * 2);
    ushort* qbf    = (ushort*)alloc((size_t)64 * 512 * 2);
    ushort* wkvt   = (ushort*)alloc((size_t)1024 * 512 * 2);
    float*  biaskv = (float*) alloc((size_t)1024 * 4);
    ushort* fc1t   = (ushort*)alloc((size_t)2048 * 512 * 2);
    ushort* fc2t   = (ushort*)alloc((size_t)512 * 2048 * 2);
    ushort* kvb    = (ushort*)alloc((size_t)16 * 4096 * 1024 * 2);
    float*  partO  = (float*) alloc((size_t)16 * 8 * 8 * 64 * 64 * 4);
    float*  partML = (float*) alloc((size_t)16 * 8 * 8 * 64 * 2 * 4);
    float*  cpart  = (float*) alloc((size_t)16 * 64 * 64 * 4);
    ushort* lnbf   = (ushort*)alloc((size_t)1024 * 512 * 2);
    ushort* hhb    = (ushort*)alloc((size_t)1024 * 2048 * 2);
    float*  fcp    = (float*) alloc((size_t)4 * 1024 * 512 * 4);
    ushort* xb     = (ushort*)alloc((size_t)16 * 4096 * 512 * 2);
    const bool use_xb = (off <= ws_size);

    prep_cls_k<<<64, 256, 0, stream>>>(E, cls0, e2dw, e2db, lng, lnbv, cls, clsln);
    prep_q_k<<<16, 512, 0, stream>>>(clsln, wq, wqb, qbf);
    wprep_k<<<2564, 256, 0, stream>>>(wk, wv, fc1w, fc2w, wkb, wvb,
                                      wkvt, fc1t, fc2t, biaskv);
    count2_k<<<dim3(64, 16), 256, 0, stream>>>(assign, cpart);

    if (use_xb) {
        xcast_k<<<16384, 256, 0, stream>>>(x, xb);
        gemm_k<0, 0, 1, 1024, 512, 512><<<4096, 512, 0, stream>>>(xb, wkvt, biaskv,
                                                                  kvb, nullptr, nullptr);
    } else {
        gemm_k<1, 0, 1, 1024, 512, 512><<<4096, 512, 0, stream>>>(x, wkvt, biaskv,
                                                                  kvb, nullptr, nullptr);
    }
    attn_k<<<dim3(8, 8, 16), 256, 0, stream>>>(qbf, kvb, assign, partO, partML);
    combine_k<<<128, 256, 0, stream>>>(partO, partML, cls, cpart, cnt, emp, mout);
    ln_rows_k<<<1024, 256, 0, stream>>>(mout, lng, lnbv, lnbf);
    gemm_k<0, 1, 0, 2048, 512, 512><<<dim3(8, 16), 512, 0, stream>>>(lnbf, fc1t, fc1b,
                                                                     hhb, nullptr, nullptr);
    gemm_k<0, 3, 0, 512, 512, 2048><<<dim3(8, 4, 4), 512, 0, stream>>>(hhb, fc2t, fc2b,
                                                                       nullptr, nullptr, fcp);
    combine2_k<<<2048, 256, 0, stream>>>(fcp, fc2b, mout);
}

// Round 17
// 279.591 us; speedup vs baseline: 1.0562x; 1.0350x over previous
//
#include <hip/hip_runtime.h>
#include <hip/hip_bf16.h>
#include <cstdint>
#include <cmath>

#define DEV static __device__ __forceinline__

typedef __attribute__((ext_vector_type(8))) short bf16x8;
typedef __attribute__((ext_vector_type(4))) float f32x4;

DEV ushort f2bf(float f) {
    union { float f; uint32_t u; } v; v.f = f;
    uint32_t r = v.u + 0x7FFFu + ((v.u >> 16) & 1u);
    return (ushort)(r >> 16);
}
DEV uint32_t pack2bf(float lo, float hi) {
    return (uint32_t)f2bf(lo) | ((uint32_t)f2bf(hi) << 16);
}
DEV float bf2f(ushort h) {
    union { uint32_t u; float f; } v; v.u = ((uint32_t)h) << 16;
    return v.f;
}
// async global->LDS, 16B per lane; LDS dest = wave-uniform base + lane*16
DEV void gld16(const ushort* g, ushort* l) {
    __builtin_amdgcn_global_load_lds(
        (const __attribute__((address_space(1))) unsigned int*)g,
        (__attribute__((address_space(3))) unsigned int*)l, 16, 0, 0);
}

// ---------------- fused prep: xcast | prep_cls | wprep | count2 in one launch ----------------
// block ranges: [0,nxb) xcast ; [nxb,nxb+64) prep_cls ; [+2564) wprep ; [+1024) count2
__global__ __launch_bounds__(256)
void prep_all_k(int nxb, const float* __restrict__ x, ushort* __restrict__ xb,
                const float* __restrict__ E, const float* __restrict__ cls0,
                const float* __restrict__ e2dw, const float* __restrict__ e2db,
                const float* __restrict__ lng, const float* __restrict__ lnbv,
                float* __restrict__ cls, ushort* __restrict__ clsln,
                const float* __restrict__ wk, const float* __restrict__ wv,
                const float* __restrict__ fc1w, const float* __restrict__ fc2w,
                const float* __restrict__ kb, const float* __restrict__ vb,
                ushort* __restrict__ wkvt, ushort* __restrict__ fc1t,
                ushort* __restrict__ fc2t, float* __restrict__ biaskv,
                const float* __restrict__ assign, float* __restrict__ cpart)
{
    __shared__ float sh[64 * 65];
    int id = blockIdx.x;
    const int tid = threadIdx.x;

    if (id < nxb) {               // ---- xcast ----
        const size_t i = (size_t)id * 256 + tid;
        const float4* s = (const float4*)(x + i * 8);
        float4 a = s[0], b = s[1];
        uint4 o;
        o.x = pack2bf(a.x, a.y); o.y = pack2bf(a.z, a.w);
        o.z = pack2bf(b.x, b.y); o.w = pack2bf(b.z, b.w);
        *(uint4*)(xb + i * 8) = o;
        return;
    }
    id -= nxb;
    if (id < 64) {                // ---- prep_cls ----
        const int k = id;
        float* Ek = sh + 512;              // 16 floats
        float2* red = (float2*)sh;         // 256 float2
        if (tid < 16) Ek[tid] = E[k * 16 + tid];
        __syncthreads();
        float vals[2];
#pragma unroll
        for (int j = 0; j < 2; j++) {
            int d = tid + j * 256;
            float a = cls0[k * 512 + d] + e2db[d];
#pragma unroll
            for (int e = 0; e < 16; e++) a += Ek[e] * e2dw[e * 512 + d];
            vals[j] = a;
            cls[k * 512 + d] = a;
        }
        // block reduce (sum, sumsq)
        red[tid] = make_float2(vals[0] + vals[1],
                               vals[0] * vals[0] + vals[1] * vals[1]);
        __syncthreads();
        for (int s2 = 128; s2 > 0; s2 >>= 1) {
            if (tid < s2) {
                float2 o = red[tid + s2];
                float2 m = red[tid];
                red[tid] = make_float2(m.x + o.x, m.y + o.y);
            }
            __syncthreads();
        }
        float2 sr = red[0];
        float mu = sr.x * (1.f / 512.f);
        float var = sr.y * (1.f / 512.f) - mu * mu;
        float inv = rsqrtf(var + 1e-5f);
#pragma unroll
        for (int j = 0; j < 2; j++) {
            int d = tid + j * 256;
            clsln[k * 512 + d] = f2bf((vals[j] - mu) * inv * lng[d] + lnbv[d]);
        }
        return;
    }
    id -= 64;
    if (id < 2564) {              // ---- wprep ----
        if (id >= 2560) {
            int i = (id - 2560) * 256 + tid;
            biaskv[i] = (i < 512) ? kb[i] : vb[i - 512];
            return;
        }
        const float* in; ushort* out; int R, C, bx, by;
        if (id < 256)        { in = wk;   out = wkvt;             R = 512;  C = 512;  int t = id;        bx = t & 15; by = t >> 4; }
        else if (id < 512)   { in = wv;   out = wkvt + 512 * 512; R = 512;  C = 512;  int t = id - 256;  bx = t & 15; by = t >> 4; }
        else if (id < 1536)  { in = fc1w; out = fc1t;             R = 512;  C = 2048; int t = id - 512;  bx = t & 63; by = t >> 6; }
        else                 { in = fc2w; out = fc2t;             R = 2048; C = 512;  int t = id - 1536; bx = t & 15; by = t >> 4; }
        float (*T)[33] = (float (*)[33])sh;
        const int c0 = bx * 32, r0 = by * 32;
        const int tx = tid & 31, ty = tid >> 5;
#pragma unroll
        for (int i = 0; i < 32; i += 8)
            T[ty + i][tx] = in[(size_t)(r0 + ty + i) * C + c0 + tx];
        __syncthreads();
#pragma unroll
        for (int i = 0; i < 32; i += 8)
            out[(size_t)(c0 + ty + i) * R + r0 + tx] = f2bf(T[tx][ty + i]);
        return;
    }
    id -= 2564;
    {                             // ---- count2 (1024 blocks) ----
        const int vt = id & 63, b = id >> 6;
        float (*T)[65] = (float (*)[65])sh;
        const int rr = tid >> 2, sg = tid & 3;
        const float4* src = (const float4*)(assign + ((size_t)b * 4096 + vt * 64 + rr) * 64 + sg * 16);
        float4 a0 = src[0], a1 = src[1], a2 = src[2], a3 = src[3];
        float* tr = &T[rr][sg * 16];
        tr[0] = a0.x; tr[1] = a0.y; tr[2] = a0.z; tr[3] = a0.w;
        tr[4] = a1.x; tr[5] = a1.y; tr[6] = a1.z; tr[7] = a1.w;
        tr[8] = a2.x; tr[9] = a2.y; tr[10] = a2.z; tr[11] = a2.w;
        tr[12] = a3.x; tr[13] = a3.y; tr[14] = a3.z; tr[15] = a3.w;
        __syncthreads();
        const int k = rr;
        float ssum = 0.f;
#pragma unroll
        for (int j = 0; j < 4; j++)
#pragma unroll
            for (int t2 = 0; t2 < 4; t2++) ssum += T[sg * 16 + j * 4 + t2][k];
        ssum += __shfl_xor(ssum, 1, 64);
        ssum += __shfl_xor(ssum, 2, 64);
        if (sg == 0) cpart[((size_t)b * 64 + k) * 64 + vt] = ssum;
    }
}

// ---------------- prep: q = clsln @ Wq + b (64x512x512, tiny) ----------------
__global__ __launch_bounds__(512)
void prep_q_k(const ushort* __restrict__ clsln, const float* __restrict__ wq,
              const float* __restrict__ wqb, ushort* __restrict__ qbf)
{
    const int kb = blockIdx.x * 4;
    const int n = threadIdx.x;
    __shared__ float Ar[4][512];
#pragma unroll
    for (int j = 0; j < 4; j++) Ar[j][n] = bf2f(clsln[(kb + j) * 512 + n]);
    __syncthreads();
    float acc[4] = {0.f, 0.f, 0.f, 0.f};
    for (int d = 0; d < 512; ++d) {
        float wv = wq[d * 512 + n];
#pragma unroll
        for (int j = 0; j < 4; j++) acc[j] += Ar[j][d] * wv;
    }
#pragma unroll
    for (int j = 0; j < 4; j++) qbf[(kb + j) * 512 + n] = f2bf(acc[j] + wqb[n]);
}

// ---------------- 128x128xBK64 bf16 MFMA GEMM, 8 waves (512 thr), single-buffer ----------------
template<int AMODE, int EPI, int SWZ, int ND, int KD, int LDK>
__global__ __launch_bounds__(512)
void gemm_k(const void* __restrict__ Ap, const ushort* __restrict__ Bt,
            const float* __restrict__ bias,
            ushort* __restrict__ o_bf, const float* __restrict__ res,
            float* __restrict__ o_f)
{
    __shared__ ushort smem[16384];
    ushort* As = smem;
    ushort* Bs = smem + 8192;
    int m0, n0;
    if (SWZ) {
        int L = blockIdx.x;
        int c = L & 7, j = L >> 3;
        m0 = (c * 64 + (j >> 3)) * 128;
        n0 = (j & 7) * 128;
    } else {
        m0 = blockIdx.x * 128;
        n0 = blockIdx.y * 128;
    }
    const int tid = threadIdx.x;
    const int w = tid >> 6, l = tid & 63;
    const int wr = w >> 2, wc = w & 3;
    const int lg = l >> 4, lr = l & 15;

    const f32x4 fzero = {0.f, 0.f, 0.f, 0.f};
    f32x4 acc[4][2];
#pragma unroll
    for (int i = 0; i < 4; i++)
#pragma unroll
        for (int j = 0; j < 2; j++) acc[i][j] = fzero;

    const int lrow8 = l >> 3;
    const int colswz = ((l & 7) ^ lrow8) * 8;
    const ushort* gB  = Bt + (size_t)(n0 + w * 16 + lrow8) * LDK + colswz;
    const ushort* gA0 = (const ushort*)Ap + (size_t)(m0 + w * 16 + lrow8) * LDK + colswz;
    const float*  gA1 = (const float*)Ap + (size_t)(m0 + w * 16 + (l >> 2)) * LDK + (l & 3) * 16;

    const int kbase = blockIdx.z * KD;
    constexpr int NT = KD / 64;
#pragma unroll
    for (int t = 0; t < NT; ++t) {
        const int kt = kbase + t * 64;
        __syncthreads();
        if (AMODE == 0) {
#pragma unroll
            for (int i = 0; i < 2; i++) {
                gld16(gA0 + (size_t)i * 8 * LDK + kt, As + (w * 16 + i * 8) * 64);
                gld16(gB + (size_t)i * 8 * LDK + kt, Bs + (w * 16 + i * 8) * 64);
            }
        } else {
            float4 av[4];
#pragma unroll
            for (int i = 0; i < 4; i++)
                av[i] = *(const float4*)(gA1 + kt + i * 4);
#pragma unroll
            for (int i = 0; i < 2; i++)
                gld16(gB + (size_t)i * 8 * LDK + kt, Bs + (w * 16 + i * 8) * 64);
            {
                int r = w * 16 + (l >> 2);
                uint2 p0, p1;
                p0.x = pack2bf(av[0].x, av[0].y); p0.y = pack2bf(av[0].z, av[0].w);
                uint2 q0; q0.x = pack2bf(av[1].x, av[1].y); q0.y = pack2bf(av[1].z, av[1].w);
                p1.x = pack2bf(av[2].x, av[2].y); p1.y = pack2bf(av[2].z, av[2].w);
                uint2 q1; q1.x = pack2bf(av[3].x, av[3].y); q1.y = pack2bf(av[3].z, av[3].w);
                int cb = (l & 3) * 32;
                *(uint2*)((char*)As + r * 128 + ((cb     ) ^ ((r & 7) << 4))) = p0;
                *(uint2*)((char*)As + r * 128 + ((cb +  8) ^ ((r & 7) << 4))) = q0;
                *(uint2*)((char*)As + r * 128 + ((cb + 16) ^ ((r & 7) << 4))) = p1;
                *(uint2*)((char*)As + r * 128 + ((cb + 24) ^ ((r & 7) << 4))) = q1;
            }
        }
        asm volatile("s_waitcnt vmcnt(0)" ::: "memory");
        __syncthreads();
#pragma unroll
        for (int kk = 0; kk < 2; kk++) {
            int kb = (kk * 32 + lg * 8) * 2;
            bf16x8 af[4], bfv[2];
#pragma unroll
            for (int mi = 0; mi < 4; mi++) {
                int row = wr * 64 + mi * 16 + lr;
                af[mi] = *(bf16x8*)((char*)As + row * 128 + (kb ^ ((row & 7) << 4)));
            }
#pragma unroll
            for (int ni = 0; ni < 2; ni++) {
                int row = wc * 32 + ni * 16 + lr;
                bfv[ni] = *(bf16x8*)((char*)Bs + row * 128 + (kb ^ ((row & 7) << 4)));
            }
#pragma unroll
            for (int mi = 0; mi < 4; mi++)
#pragma unroll
                for (int ni = 0; ni < 2; ni++)
                    acc[mi][ni] = __builtin_amdgcn_mfma_f32_16x16x32_bf16(af[mi], bfv[ni], acc[mi][ni], 0, 0, 0);
        }
    }

    if (EPI == 0) {
        __syncthreads();
#pragma unroll
        for (int mi = 0; mi < 4; mi++)
#pragma unroll
            for (int ni = 0; ni < 2; ni++)
#pragma unroll
                for (int r = 0; r < 4; r++) {
                    int rl = wr * 64 + mi * 16 + lg * 4 + r;
                    int cl = wc * 32 + ni * 16 + lr;
                    int byteoff = rl * 256 + ((cl * 2) ^ ((rl & 7) << 4));
                    *(ushort*)((char*)smem + byteoff) = f2bf(acc[mi][ni][r] + bias[n0 + cl]);
                }
        __syncthreads();
        const int row = tid >> 2, sg2 = tid & 3;
        uint4* dq = (uint4*)(o_bf + (size_t)(m0 + row) * ND + n0 + sg2 * 32);
#pragma unroll
        for (int q2 = 0; q2 < 4; q2++) {
            int byteoff = row * 256 + ((sg2 * 64 + q2 * 16) ^ ((row & 7) << 4));
            dq[q2] = *(const uint4*)((char*)smem + byteoff);
        }
    } else {
        float* ofz = o_f;
        if (EPI == 3)
            ofz = o_f + (size_t)blockIdx.z * (size_t)gridDim.x * 128 * ND;
#pragma unroll
        for (int mi = 0; mi < 4; mi++) {
#pragma unroll
            for (int ni = 0; ni < 2; ni++) {
#pragma unroll
                for (int r = 0; r < 4; r++) {
                    int row = m0 + wr * 64 + mi * 16 + lg * 4 + r;
                    int col = n0 + wc * 32 + ni * 16 + lr;
                    if (EPI == 1) {
                        float c = acc[mi][ni][r] + bias[col];
                        float gg = 0.5f * c * (1.f + erff(c * 0.70710678f));
                        o_bf[(size_t)row * ND + col] = f2bf(gg);
                    } else if (EPI == 2) {
                        float c = acc[mi][ni][r] + bias[col];
                        o_f[(size_t)row * ND + col] = c + res[(size_t)row * ND + col];
                    } else {
                        ofz[(size_t)row * ND + col] = acc[mi][ni][r];
                    }
                }
            }
        }
    }
}

// ---------------- split-K combine for fc2: mout += bias + sum_z partial ----------------
__global__ __launch_bounds__(256)
void combine2_k(const float* __restrict__ fcp, const float* __restrict__ fc2b,
                float* __restrict__ mout)
{
    const int i = blockIdx.x * 256 + threadIdx.x;   // 0..524287
    const int col = i & 511;
    float s = fc2b[col] + fcp[i] + fcp[i + 524288] + fcp[i + 2 * 524288] + fcp[i + 3 * 524288];
    mout[i] += s;
}

// ---------------- flash attention (split-KV partials); K|V packed rows of 1024 ----------------
__global__ __launch_bounds__(256)
void attn_k(const ushort* __restrict__ qbf, const ushort* __restrict__ kv,
            const float* __restrict__ assign,
            float* __restrict__ partO, float* __restrict__ partML)
{
    const int h = blockIdx.x, s = blockIdx.y, b = blockIdx.z;
    __shared__ ushort Qs[64 * 64];
    __shared__ ushort Ks[64 * 64];
    __shared__ ushort Vt[64 * 64];
    __shared__ ushort Ps[64 * 64];
    __shared__ float  Lm[64 * 64];
    const int tid = threadIdx.x;
    const int w = tid >> 6, l = tid & 63, lg = l >> 4, lr = l & 15;
    const int rr = tid >> 2, qt = tid & 3;

    { // stage Q once
        const uint4* src = (const uint4*)(qbf + rr * 512 + h * 64 + qt * 16);
        uint4 t0 = src[0], t1 = src[1];
        int kb = qt * 32;
        *(uint4*)((char*)Qs + rr * 128 + ( kb       ^ ((rr & 7) << 4))) = t0;
        *(uint4*)((char*)Qs + rr * 128 + ((kb + 16) ^ ((rr & 7) << 4))) = t1;
    }

    const f32x4 fzero = {0.f, 0.f, 0.f, 0.f};
    f32x4 oacc[4];
#pragma unroll
    for (int ni = 0; ni < 4; ni++) oacc[ni] = fzero;
    float m_run[4], l_run[4];
#pragma unroll
    for (int r = 0; r < 4; r++) { m_run[r] = -3e38f; l_run[r] = 0.f; }

    const int v00 = s * 512;

    for (int c = 0; c < 8; ++c) {
        const int vb = v00 + c * 64;
        __syncthreads();
        {
            const size_t rowb = ((size_t)b * 4096 + vb + rr) * 1024 + h * 64;
            const uint4* srck = (const uint4*)(kv + rowb + qt * 16);
            uint4 k0 = srck[0], k1 = srck[1];
            int kb = qt * 32;
            *(uint4*)((char*)Ks + rr * 128 + ( kb       ^ ((rr & 7) << 4))) = k0;
            *(uint4*)((char*)Ks + rr * 128 + ((kb + 16) ^ ((rr & 7) << 4))) = k1;
            const ushort* srcv = kv + rowb + 512 + qt * 16;
            ushort vvv[16];
            *(uint4*)&vvv[0] = ((const uint4*)srcv)[0];
            *(uint4*)&vvv[8] = ((const uint4*)srcv)[1];
#pragma unroll
            for (int i = 0; i < 16; i++) {
                int dk = qt * 16 + i;
                *(ushort*)((char*)Vt + dk * 128 + ((rr * 2) ^ ((dk & 7) << 4))) = vvv[i];
            }
            const float4* srca = (const float4*)(assign + ((size_t)b * 4096 + vb + rr) * 64 + qt * 16);
            float4 A0 = srca[0], A1 = srca[1], A2 = srca[2], A3 = srca[3];
            float av[16] = {A0.x, A0.y, A0.z, A0.w, A1.x, A1.y, A1.z, A1.w,
                            A2.x, A2.y, A2.z, A2.w, A3.x, A3.y, A3.z, A3.w};
#pragma unroll
            for (int i = 0; i < 16; i++)
                Lm[(qt * 16 + i) * 64 + rr] = __logf(fminf(fmaxf(av[i], 0.f), 1.f) + 1e-6f);
        }
        __syncthreads();

        f32x4 sacc[4];
#pragma unroll
        for (int ni = 0; ni < 4; ni++) sacc[ni] = fzero;
        __builtin_amdgcn_s_setprio(1);
#pragma unroll
        for (int kk = 0; kk < 2; kk++) {
            int kb = (kk * 32 + lg * 8) * 2;
            int qrow = w * 16 + lr;
            bf16x8 aq = *(bf16x8*)((char*)Qs + qrow * 128 + (kb ^ ((qrow & 7) << 4)));
#pragma unroll
            for (int ni = 0; ni < 4; ni++) {
                int kr = ni * 16 + lr;
                bf16x8 bk = *(bf16x8*)((char*)Ks + kr * 128 + (kb ^ ((kr & 7) << 4)));
                sacc[ni] = __builtin_amdgcn_mfma_f32_16x16x32_bf16(aq, bk, sacc[ni], 0, 0, 0);
            }
        }
        __builtin_amdgcn_s_setprio(0);
        float sv[4][4], mx[4];
#pragma unroll
        for (int r = 0; r < 4; r++) {
            int q = w * 16 + lg * 4 + r;
            float m_ = -3e38f;
#pragma unroll
            for (int ni = 0; ni < 4; ni++) {
                float xx = sacc[ni][r] * 0.125f + Lm[q * 64 + ni * 16 + lr];
                sv[ni][r] = xx;
                m_ = fmaxf(m_, xx);
            }
            mx[r] = m_;
        }
#pragma unroll
        for (int off = 1; off < 16; off <<= 1)
#pragma unroll
            for (int r = 0; r < 4; r++) mx[r] = fmaxf(mx[r], __shfl_xor(mx[r], off, 64));
        float scale[4], lad[4];
#pragma unroll
        for (int r = 0; r < 4; r++) {
            float mn = fmaxf(m_run[r], mx[r]);
            scale[r] = __expf(m_run[r] - mn);
            m_run[r] = mn;
            float ls = 0.f;
#pragma unroll
            for (int ni = 0; ni < 4; ni++) {
                float p = __expf(sv[ni][r] - mn);
                sv[ni][r] = p;
                ls += p;
            }
            lad[r] = ls;
        }
#pragma unroll
        for (int off = 1; off < 16; off <<= 1)
#pragma unroll
            for (int r = 0; r < 4; r++) lad[r] += __shfl_xor(lad[r], off, 64);
#pragma unroll
        for (int r = 0; r < 4; r++) l_run[r] = l_run[r] * scale[r] + lad[r];
#pragma unroll
        for (int ni = 0; ni < 4; ni++) {
            f32x4 o = oacc[ni];
            o[0] *= scale[0]; o[1] *= scale[1]; o[2] *= scale[2]; o[3] *= scale[3];
            oacc[ni] = o;
        }
#pragma unroll
        for (int ni = 0; ni < 4; ni++)
#pragma unroll
            for (int r = 0; r < 4; r++) {
                int q = w * 16 + lg * 4 + r;
                int key = ni * 16 + lr;
                *(ushort*)((char*)Ps + q * 128 + ((key * 2) ^ ((q & 7) << 4))) = f2bf(sv[ni][r]);
            }
        __builtin_amdgcn_s_setprio(1);
#pragma unroll
        for (int kk = 0; kk < 2; kk++) {
            int kb = (kk * 32 + lg * 8) * 2;
            int prow = w * 16 + lr;
            bf16x8 ap = *(bf16x8*)((char*)Ps + prow * 128 + (kb ^ ((prow & 7) << 4)));
#pragma unroll
            for (int ni = 0; ni < 4; ni++) {
                int dk = ni * 16 + lr;
                bf16x8 bv = *(bf16x8*)((char*)Vt + dk * 128 + (kb ^ ((dk & 7) << 4)));
                oacc[ni] = __builtin_amdgcn_mfma_f32_16x16x32_bf16(ap, bv, oacc[ni], 0, 0, 0);
            }
        }
        __builtin_amdgcn_s_setprio(0);
    }
    const size_t ob = ((size_t)((b * 8 + h) * 8 + s)) * 4096;
#pragma unroll
    for (int ni = 0; ni < 4; ni++)
#pragma unroll
        for (int r = 0; r < 4; r++) {
            int q = w * 16 + lg * 4 + r;
            int dk = ni * 16 + lr;
            partO[ob + q * 64 + dk] = oacc[ni][r];
        }
    if (lr == 0) {
#pragma unroll
        for (int r = 0; r < 4; r++) {
            int q = w * 16 + lg * 4 + r;
            partML[((b * 8 + h) * 8 + s) * 128 + q * 2 + 0] = m_run[r];
            partML[((b * 8 + h) * 8 + s) * 128 + q * 2 + 1] = l_run[r];
        }
    }
}

// ---------------- merge split-KV partials, empty-slot fallback; also finalizes counts ----------------
__global__ __launch_bounds__(256)
void combine_k(const float* __restrict__ partO, const float* __restrict__ partML,
               const float* __restrict__ cls, const float* __restrict__ cpart,
               float* __restrict__ cnt, float* __restrict__ emp,
               float* __restrict__ mout)
{
    const int bh = blockIdx.x, b = bh >> 3, h = bh & 7;
    __shared__ float Ms[64], Ls[64], Cs[64];
    const int tid = threadIdx.x;
    if (tid < 64) {
        float M = -3e38f;
#pragma unroll
        for (int s2 = 0; s2 < 8; s2++) M = fmaxf(M, partML[(bh * 8 + s2) * 128 + tid * 2]);
        float L = 0.f;
#pragma unroll
        for (int s2 = 0; s2 < 8; s2++) {
            float m_ = partML[(bh * 8 + s2) * 128 + tid * 2];
            float l_ = partML[(bh * 8 + s2) * 128 + tid * 2 + 1];
            L += l_ * __expf(m_ - M);
        }
        Ms[tid] = M; Ls[tid] = L;
        const float4* p = (const float4*)(cpart + ((size_t)b * 64 + tid) * 64);
        float cs = 0.f;
#pragma unroll
        for (int t = 0; t < 16; t++) {
            float4 f = p[t];
            cs += f.x + f.y + f.z + f.w;
        }
        Cs[tid] = cs;
        if (h == 0) {
            cnt[b * 64 + tid] = cs;
            emp[b * 64 + tid] = (cs <= 1e-6f) ? 1.f : 0.f;
        }
    }
    __syncthreads();
#pragma unroll
    for (int i = 0; i < 16; i++) {
        int e = i * 256 + tid;
        int q = e >> 6, dk = e & 63;
        float o = 0.f;
#pragma unroll
        for (int s2 = 0; s2 < 8; s2++) {
            float m_ = partML[(bh * 8 + s2) * 128 + q * 2];
            o += partO[(size_t)(bh * 8 + s2) * 4096 + e] * __expf(m_ - Ms[q]);
        }
        float val = o / (Ls[q] + 1e-8f);
        if (Cs[q] <= 1e-6f) val = cls[q * 512 + h * 64 + dk];
        mout[((size_t)b * 64 + q) * 512 + h * 64 + dk] = val;
    }
}

// ---------------- LN over rows of m (pre-FFN) ----------------
__global__ __launch_bounds__(256)
void ln_rows_k(const float* __restrict__ m, const float* __restrict__ g,
               const float* __restrict__ be, ushort* __restrict__ out)
{
    const int r = blockIdx.x, tid = threadIdx.x;
    float v0 = m[(size_t)r * 512 + tid];
    float v1 = m[(size_t)r * 512 + tid + 256];
    __shared__ float2 red[256];
    red[tid] = make_float2(v0 + v1, v0 * v0 + v1 * v1);
    __syncthreads();
    for (int s2 = 128; s2 > 0; s2 >>= 1) {
        if (tid < s2) {
            float2 o = red[tid + s2];
            float2 m2 = red[tid];
            red[tid] = make_float2(m2.x + o.x, m2.y + o.y);
        }
        __syncthreads();
    }
    float2 sr = red[0];
    float mu = sr.x * (1.f / 512.f);
    float var = sr.y * (1.f / 512.f) - mu * mu;
    float inv = rsqrtf(var + 1e-5f);
    out[(size_t)r * 512 + tid]       = f2bf((v0 - mu) * inv * g[tid] + be[tid]);
    out[(size_t)r * 512 + tid + 256] = f2bf((v1 - mu) * inv * g[tid + 256] + be[tid + 256]);
}

extern "C" void kernel_launch(void* const* d_in, const int* in_sizes, int n_in,
                              void* d_out, int out_size, void* d_ws, size_t ws_size,
                              hipStream_t stream)
{
    const float* x      = (const float*)d_in[0];
    const float* assign = (const float*)d_in[1];
    const float* E      = (const float*)d_in[2];
    const float* cls0   = (const float*)d_in[3];
    const float* e2dw   = (const float*)d_in[4];
    const float* e2db   = (const float*)d_in[5];
    const float* wq     = (const float*)d_in[6];
    const float* wqb    = (const float*)d_in[7];
    const float* wk     = (const float*)d_in[8];
    const float* wkb    = (const float*)d_in[9];
    const float* wv     = (const float*)d_in[10];
    const float* wvb    = (const float*)d_in[11];
    const float* lng    = (const float*)d_in[12];
    const float* lnbv   = (const float*)d_in[13];
    const float* fc1w   = (const float*)d_in[14];
    const float* fc1b   = (const float*)d_in[15];
    const float* fc2w   = (const float*)d_in[16];
    const float* fc2b   = (const float*)d_in[17];

    float* mout = (float*)d_out;
    float* cnt  = mout + (size_t)16 * 64 * 512;
    float* emp  = cnt + 16 * 64;

    char* ws = (char*)d_ws;
    size_t off = 0;
    auto alloc = [&](size_t bytes) -> char* {
        char* p = ws + off;
        off = (off + bytes + 255) & ~(size_t)255;
        return p;
    };
    float*  cls    = (float*) alloc((size_t)64 * 512 * 4);
    ushort* clsln  = (ushort*)alloc((size_t)64 * 512 * 2);
    ushort* qbf    = (ushort*)alloc((size_t)64 * 512 * 2);
    ushort* wkvt   = (ushort*)alloc((size_t)1024 * 512 * 2);
    float*  biaskv = (float*) alloc((size_t)1024 * 4);
    ushort* fc1t   = (ushort*)alloc((size_t)2048 * 512 * 2);
    ushort* fc2t   = (ushort*)alloc((size_t)512 * 2048 * 2);
    ushort* kvb    = (ushort*)alloc((size_t)16 * 4096 * 1024 * 2);
    float*  partO  = (float*) alloc((size_t)16 * 8 * 8 * 64 * 64 * 4);
    float*  partML = (float*) alloc((size_t)16 * 8 * 8 * 64 * 2 * 4);
    float*  cpart  = (float*) alloc((size_t)16 * 64 * 64 * 4);
    ushort* lnbf   = (ushort*)alloc((size_t)1024 * 512 * 2);
    ushort* hhb    = (ushort*)alloc((size_t)1024 * 2048 * 2);
    float*  fcp    = (float*) alloc((size_t)4 * 1024 * 512 * 4);
    ushort* xb     = (ushort*)alloc((size_t)16 * 4096 * 512 * 2);
    const bool use_xb = (off <= ws_size);

    const int nxb = use_xb ? 16384 : 0;
    prep_all_k<<<nxb + 64 + 2564 + 1024, 256, 0, stream>>>(
        nxb, x, xb, E, cls0, e2dw, e2db, lng, lnbv, cls, clsln,
        wk, wv, fc1w, fc2w, wkb, wvb, wkvt, fc1t, fc2t, biaskv,
        assign, cpart);
    prep_q_k<<<16, 512, 0, stream>>>(clsln, wq, wqb, qbf);

    if (use_xb) {
        gemm_k<0, 0, 1, 1024, 512, 512><<<4096, 512, 0, stream>>>(xb, wkvt, biaskv,
                                                                  kvb, nullptr, nullptr);
    } else {
        gemm_k<1, 0, 1, 1024, 512, 512><<<4096, 512, 0, stream>>>(x, wkvt, biaskv,
                                                                  kvb, nullptr, nullptr);
    }
    attn_k<<<dim3(8, 8, 16), 256, 0, stream>>>(qbf, kvb, assign, partO, partML);
    combine_k<<<128, 256, 0, stream>>>(partO, partML, cls, cpart, cnt, emp, mout);
    ln_rows_k<<<1024, 256, 0, stream>>>(mout, lng, lnbv, lnbf);
    gemm_k<0, 1, 0, 2048, 512, 512><<<dim3(8, 16), 512, 0, stream>>>(lnbf, fc1t, fc1b,
                                                                     hhb, nullptr, nullptr);
    gemm_k<0, 3, 0, 512, 512, 2048><<<dim3(8, 4, 4), 512, 0, stream>>>(hhb, fc2t, fc2b,
                                                                       nullptr, nullptr, fcp);
    combine2_k<<<2048, 256, 0, stream>>>(fcp, fc2b, mout);
}

// Round 18
// 274.937 us; speedup vs baseline: 1.0741x; 1.0169x over previous
//
#include <hip/hip_runtime.h>
#include <hip/hip_bf16.h>
#include <cstdint>
#include <cmath>

#define DEV static __device__ __forceinline__

typedef __attribute__((ext_vector_type(8))) short bf16x8;
typedef __attribute__((ext_vector_type(4))) float f32x4;

DEV ushort f2bf(float f) {
    union { float f; uint32_t u; } v; v.f = f;
    uint32_t r = v.u + 0x7FFFu + ((v.u >> 16) & 1u);
    return (ushort)(r >> 16);
}
DEV uint32_t pack2bf(float lo, float hi) {
    return (uint32_t)f2bf(lo) | ((uint32_t)f2bf(hi) << 16);
}
DEV float bf2f(ushort h) {
    union { uint32_t u; float f; } v; v.u = ((uint32_t)h) << 16;
    return v.f;
}
// async global->LDS, 16B per lane; LDS dest = wave-uniform base + lane*16
DEV void gld16(const ushort* g, ushort* l) {
    __builtin_amdgcn_global_load_lds(
        (const __attribute__((address_space(1))) unsigned int*)g,
        (__attribute__((address_space(3))) unsigned int*)l, 16, 0, 0);
}

// ---------------- fused prep: xcast | prep_cls(+q) | wprep | count2 in one launch ----------------
// block ranges: [0,nxb) xcast ; [nxb,nxb+64) prep_cls+q ; [+2564) wprep ; [+1024) count2
__global__ __launch_bounds__(256)
void prep_all_k(int nxb, const float* __restrict__ x, ushort* __restrict__ xb,
                const float* __restrict__ E, const float* __restrict__ cls0,
                const float* __restrict__ e2dw, const float* __restrict__ e2db,
                const float* __restrict__ lng, const float* __restrict__ lnbv,
                const float* __restrict__ wq, const float* __restrict__ wqb,
                float* __restrict__ cls, ushort* __restrict__ qbf,
                const float* __restrict__ wk, const float* __restrict__ wv,
                const float* __restrict__ fc1w, const float* __restrict__ fc2w,
                const float* __restrict__ kb, const float* __restrict__ vb,
                ushort* __restrict__ wkvt, ushort* __restrict__ fc1t,
                ushort* __restrict__ fc2t, float* __restrict__ biaskv,
                const float* __restrict__ assign, float* __restrict__ cpart)
{
    __shared__ float sh[64 * 65];
    int id = blockIdx.x;
    const int tid = threadIdx.x;

    if (id < nxb) {               // ---- xcast ----
        const size_t i = (size_t)id * 256 + tid;
        const float4* s = (const float4*)(x + i * 8);
        float4 a = s[0], b = s[1];
        uint4 o;
        o.x = pack2bf(a.x, a.y); o.y = pack2bf(a.z, a.w);
        o.z = pack2bf(b.x, b.y); o.w = pack2bf(b.z, b.w);
        *(uint4*)(xb + i * 8) = o;
        return;
    }
    id -= nxb;
    if (id < 64) {                // ---- prep_cls + q projection ----
        const int k = id;
        float* lnv = sh;                       // 512 floats (LN'd row)
        float* Ek = sh + 512;                  // 16 floats
        float2* red = (float2*)(sh + 544);     // 256 float2
        if (tid < 16) Ek[tid] = E[k * 16 + tid];
        __syncthreads();
        float vals[2];
#pragma unroll
        for (int j = 0; j < 2; j++) {
            int d = tid + j * 256;
            float a = cls0[k * 512 + d] + e2db[d];
#pragma unroll
            for (int e = 0; e < 16; e++) a += Ek[e] * e2dw[e * 512 + d];
            vals[j] = a;
            cls[k * 512 + d] = a;
        }
        red[tid] = make_float2(vals[0] + vals[1],
                               vals[0] * vals[0] + vals[1] * vals[1]);
        __syncthreads();
        for (int s2 = 128; s2 > 0; s2 >>= 1) {
            if (tid < s2) {
                float2 o = red[tid + s2];
                float2 m = red[tid];
                red[tid] = make_float2(m.x + o.x, m.y + o.y);
            }
            __syncthreads();
        }
        float2 sr = red[0];
        float mu = sr.x * (1.f / 512.f);
        float var = sr.y * (1.f / 512.f) - mu * mu;
        float inv = rsqrtf(var + 1e-5f);
        __syncthreads();
#pragma unroll
        for (int j = 0; j < 2; j++) {
            int d = tid + j * 256;
            lnv[d] = (vals[j] - mu) * inv * lng[d] + lnbv[d];
        }
        __syncthreads();
        // q[k][n] = sum_d lnv[d] * wq[d][n] + wqb[n], 2 cols/thread
#pragma unroll
        for (int j = 0; j < 2; j++) {
            int n = tid + j * 256;
            float acc = 0.f;
            for (int d = 0; d < 512; ++d)
                acc += lnv[d] * wq[d * 512 + n];
            qbf[k * 512 + n] = f2bf(acc + wqb[n]);
        }
        return;
    }
    id -= 64;
    if (id < 2564) {              // ---- wprep ----
        if (id >= 2560) {
            int i = (id - 2560) * 256 + tid;
            biaskv[i] = (i < 512) ? kb[i] : vb[i - 512];
            return;
        }
        const float* in; ushort* out; int R, C, bx, by;
        if (id < 256)        { in = wk;   out = wkvt;             R = 512;  C = 512;  int t = id;        bx = t & 15; by = t >> 4; }
        else if (id < 512)   { in = wv;   out = wkvt + 512 * 512; R = 512;  C = 512;  int t = id - 256;  bx = t & 15; by = t >> 4; }
        else if (id < 1536)  { in = fc1w; out = fc1t;             R = 512;  C = 2048; int t = id - 512;  bx = t & 63; by = t >> 6; }
        else                 { in = fc2w; out = fc2t;             R = 2048; C = 512;  int t = id - 1536; bx = t & 15; by = t >> 4; }
        float (*T)[33] = (float (*)[33])sh;
        const int c0 = bx * 32, r0 = by * 32;
        const int tx = tid & 31, ty = tid >> 5;
#pragma unroll
        for (int i = 0; i < 32; i += 8)
            T[ty + i][tx] = in[(size_t)(r0 + ty + i) * C + c0 + tx];
        __syncthreads();
#pragma unroll
        for (int i = 0; i < 32; i += 8)
            out[(size_t)(c0 + ty + i) * R + r0 + tx] = f2bf(T[tx][ty + i]);
        return;
    }
    id -= 2564;
    {                             // ---- count2 (1024 blocks) ----
        const int vt = id & 63, b = id >> 6;
        float (*T)[65] = (float (*)[65])sh;
        const int rr = tid >> 2, sg = tid & 3;
        const float4* src = (const float4*)(assign + ((size_t)b * 4096 + vt * 64 + rr) * 64 + sg * 16);
        float4 a0 = src[0], a1 = src[1], a2 = src[2], a3 = src[3];
        float* tr = &T[rr][sg * 16];
        tr[0] = a0.x; tr[1] = a0.y; tr[2] = a0.z; tr[3] = a0.w;
        tr[4] = a1.x; tr[5] = a1.y; tr[6] = a1.z; tr[7] = a1.w;
        tr[8] = a2.x; tr[9] = a2.y; tr[10] = a2.z; tr[11] = a2.w;
        tr[12] = a3.x; tr[13] = a3.y; tr[14] = a3.z; tr[15] = a3.w;
        __syncthreads();
        const int k = rr;
        float ssum = 0.f;
#pragma unroll
        for (int j = 0; j < 4; j++)
#pragma unroll
            for (int t2 = 0; t2 < 4; t2++) ssum += T[sg * 16 + j * 4 + t2][k];
        ssum += __shfl_xor(ssum, 1, 64);
        ssum += __shfl_xor(ssum, 2, 64);
        if (sg == 0) cpart[((size_t)b * 64 + k) * 64 + vt] = ssum;
    }
}

// ---------------- 128x128xBK64 bf16 MFMA GEMM, 8 waves (512 thr), single-buffer ----------------
template<int AMODE, int EPI, int SWZ, int ND, int KD, int LDK>
__global__ __launch_bounds__(512)
void gemm_k(const void* __restrict__ Ap, const ushort* __restrict__ Bt,
            const float* __restrict__ bias,
            ushort* __restrict__ o_bf, const float* __restrict__ res,
            float* __restrict__ o_f)
{
    __shared__ ushort smem[16384];
    ushort* As = smem;
    ushort* Bs = smem + 8192;
    int m0, n0;
    if (SWZ) {
        int L = blockIdx.x;
        int c = L & 7, j = L >> 3;
        m0 = (c * 64 + (j >> 3)) * 128;
        n0 = (j & 7) * 128;
    } else {
        m0 = blockIdx.x * 128;
        n0 = blockIdx.y * 128;
    }
    const int tid = threadIdx.x;
    const int w = tid >> 6, l = tid & 63;
    const int wr = w >> 2, wc = w & 3;
    const int lg = l >> 4, lr = l & 15;

    const f32x4 fzero = {0.f, 0.f, 0.f, 0.f};
    f32x4 acc[4][2];
#pragma unroll
    for (int i = 0; i < 4; i++)
#pragma unroll
        for (int j = 0; j < 2; j++) acc[i][j] = fzero;

    const int lrow8 = l >> 3;
    const int colswz = ((l & 7) ^ lrow8) * 8;
    const ushort* gB  = Bt + (size_t)(n0 + w * 16 + lrow8) * LDK + colswz;
    const ushort* gA0 = (const ushort*)Ap + (size_t)(m0 + w * 16 + lrow8) * LDK + colswz;
    const float*  gA1 = (const float*)Ap + (size_t)(m0 + w * 16 + (l >> 2)) * LDK + (l & 3) * 16;

    const int kbase = blockIdx.z * KD;
    constexpr int NT = KD / 64;
#pragma unroll
    for (int t = 0; t < NT; ++t) {
        const int kt = kbase + t * 64;
        __syncthreads();
        if (AMODE == 0) {
#pragma unroll
            for (int i = 0; i < 2; i++) {
                gld16(gA0 + (size_t)i * 8 * LDK + kt, As + (w * 16 + i * 8) * 64);
                gld16(gB + (size_t)i * 8 * LDK + kt, Bs + (w * 16 + i * 8) * 64);
            }
        } else {
            float4 av[4];
#pragma unroll
            for (int i = 0; i < 4; i++)
                av[i] = *(const float4*)(gA1 + kt + i * 4);
#pragma unroll
            for (int i = 0; i < 2; i++)
                gld16(gB + (size_t)i * 8 * LDK + kt, Bs + (w * 16 + i * 8) * 64);
            {
                int r = w * 16 + (l >> 2);
                uint2 p0, p1;
                p0.x = pack2bf(av[0].x, av[0].y); p0.y = pack2bf(av[0].z, av[0].w);
                uint2 q0; q0.x = pack2bf(av[1].x, av[1].y); q0.y = pack2bf(av[1].z, av[1].w);
                p1.x = pack2bf(av[2].x, av[2].y); p1.y = pack2bf(av[2].z, av[2].w);
                uint2 q1; q1.x = pack2bf(av[3].x, av[3].y); q1.y = pack2bf(av[3].z, av[3].w);
                int cb = (l & 3) * 32;
                *(uint2*)((char*)As + r * 128 + ((cb     ) ^ ((r & 7) << 4))) = p0;
                *(uint2*)((char*)As + r * 128 + ((cb +  8) ^ ((r & 7) << 4))) = q0;
                *(uint2*)((char*)As + r * 128 + ((cb + 16) ^ ((r & 7) << 4))) = p1;
                *(uint2*)((char*)As + r * 128 + ((cb + 24) ^ ((r & 7) << 4))) = q1;
            }
        }
        asm volatile("s_waitcnt vmcnt(0)" ::: "memory");
        __syncthreads();
#pragma unroll
        for (int kk = 0; kk < 2; kk++) {
            int kb = (kk * 32 + lg * 8) * 2;
            bf16x8 af[4], bfv[2];
#pragma unroll
            for (int mi = 0; mi < 4; mi++) {
                int row = wr * 64 + mi * 16 + lr;
                af[mi] = *(bf16x8*)((char*)As + row * 128 + (kb ^ ((row & 7) << 4)));
            }
#pragma unroll
            for (int ni = 0; ni < 2; ni++) {
                int row = wc * 32 + ni * 16 + lr;
                bfv[ni] = *(bf16x8*)((char*)Bs + row * 128 + (kb ^ ((row & 7) << 4)));
            }
#pragma unroll
            for (int mi = 0; mi < 4; mi++)
#pragma unroll
                for (int ni = 0; ni < 2; ni++)
                    acc[mi][ni] = __builtin_amdgcn_mfma_f32_16x16x32_bf16(af[mi], bfv[ni], acc[mi][ni], 0, 0, 0);
        }
    }

    if (EPI == 0) {
        __syncthreads();
#pragma unroll
        for (int mi = 0; mi < 4; mi++)
#pragma unroll
            for (int ni = 0; ni < 2; ni++)
#pragma unroll
                for (int r = 0; r < 4; r++) {
                    int rl = wr * 64 + mi * 16 + lg * 4 + r;
                    int cl = wc * 32 + ni * 16 + lr;
                    int byteoff = rl * 256 + ((cl * 2) ^ ((rl & 7) << 4));
                    *(ushort*)((char*)smem + byteoff) = f2bf(acc[mi][ni][r] + bias[n0 + cl]);
                }
        __syncthreads();
        const int row = tid >> 2, sg2 = tid & 3;
        uint4* dq = (uint4*)(o_bf + (size_t)(m0 + row) * ND + n0 + sg2 * 32);
#pragma unroll
        for (int q2 = 0; q2 < 4; q2++) {
            int byteoff = row * 256 + ((sg2 * 64 + q2 * 16) ^ ((row & 7) << 4));
            dq[q2] = *(const uint4*)((char*)smem + byteoff);
        }
    } else {
        float* ofz = o_f;
        if (EPI == 3)
            ofz = o_f + (size_t)blockIdx.z * (size_t)gridDim.x * 128 * ND;
#pragma unroll
        for (int mi = 0; mi < 4; mi++) {
#pragma unroll
            for (int ni = 0; ni < 2; ni++) {
#pragma unroll
                for (int r = 0; r < 4; r++) {
                    int row = m0 + wr * 64 + mi * 16 + lg * 4 + r;
                    int col = n0 + wc * 32 + ni * 16 + lr;
                    if (EPI == 1) {
                        float c = acc[mi][ni][r] + bias[col];
                        float gg = 0.5f * c * (1.f + erff(c * 0.70710678f));
                        o_bf[(size_t)row * ND + col] = f2bf(gg);
                    } else if (EPI == 2) {
                        float c = acc[mi][ni][r] + bias[col];
                        o_f[(size_t)row * ND + col] = c + res[(size_t)row * ND + col];
                    } else {
                        ofz[(size_t)row * ND + col] = acc[mi][ni][r];
                    }
                }
            }
        }
    }
}

// ---------------- split-K combine for fc2: mout += bias + sum_z partial ----------------
__global__ __launch_bounds__(256)
void combine2_k(const float* __restrict__ fcp, const float* __restrict__ fc2b,
                float* __restrict__ mout)
{
    const int i = blockIdx.x * 256 + threadIdx.x;   // 0..524287
    const int col = i & 511;
    float s = fc2b[col] + fcp[i] + fcp[i + 524288] + fcp[i + 2 * 524288] + fcp[i + 3 * 524288];
    mout[i] += s;
}

// ---------------- flash attention (split-KV=4 partials); K|V packed rows of 1024 ----------------
// h innermost for assign L2 reuse; setprio on MFMA clusters; 1024 keys per block (16 chunks).
__global__ __launch_bounds__(256)
void attn_k(const ushort* __restrict__ qbf, const ushort* __restrict__ kv,
            const float* __restrict__ assign,
            float* __restrict__ partO, float* __restrict__ partML)
{
    const int h = blockIdx.x, s = blockIdx.y, b = blockIdx.z;
    __shared__ ushort Qs[64 * 64];
    __shared__ ushort Ks[64 * 64];
    __shared__ ushort Vt[64 * 64];
    __shared__ ushort Ps[64 * 64];
    __shared__ float  Lm[64 * 64];
    const int tid = threadIdx.x;
    const int w = tid >> 6, l = tid & 63, lg = l >> 4, lr = l & 15;
    const int rr = tid >> 2, qt = tid & 3;

    { // stage Q once
        const uint4* src = (const uint4*)(qbf + rr * 512 + h * 64 + qt * 16);
        uint4 t0 = src[0], t1 = src[1];
        int kb = qt * 32;
        *(uint4*)((char*)Qs + rr * 128 + ( kb       ^ ((rr & 7) << 4))) = t0;
        *(uint4*)((char*)Qs + rr * 128 + ((kb + 16) ^ ((rr & 7) << 4))) = t1;
    }

    const f32x4 fzero = {0.f, 0.f, 0.f, 0.f};
    f32x4 oacc[4];
#pragma unroll
    for (int ni = 0; ni < 4; ni++) oacc[ni] = fzero;
    float m_run[4], l_run[4];
#pragma unroll
    for (int r = 0; r < 4; r++) { m_run[r] = -3e38f; l_run[r] = 0.f; }

    const int v00 = s * 1024;

    for (int c = 0; c < 16; ++c) {
        const int vb = v00 + c * 64;
        __syncthreads();
        {
            const size_t rowb = ((size_t)b * 4096 + vb + rr) * 1024 + h * 64;
            const uint4* srck = (const uint4*)(kv + rowb + qt * 16);
            uint4 k0 = srck[0], k1 = srck[1];
            int kb = qt * 32;
            *(uint4*)((char*)Ks + rr * 128 + ( kb       ^ ((rr & 7) << 4))) = k0;
            *(uint4*)((char*)Ks + rr * 128 + ((kb + 16) ^ ((rr & 7) << 4))) = k1;
            const ushort* srcv = kv + rowb + 512 + qt * 16;
            ushort vvv[16];
            *(uint4*)&vvv[0] = ((const uint4*)srcv)[0];
            *(uint4*)&vvv[8] = ((const uint4*)srcv)[1];
#pragma unroll
            for (int i = 0; i < 16; i++) {
                int dk = qt * 16 + i;
                *(ushort*)((char*)Vt + dk * 128 + ((rr * 2) ^ ((dk & 7) << 4))) = vvv[i];
            }
            const float4* srca = (const float4*)(assign + ((size_t)b * 4096 + vb + rr) * 64 + qt * 16);
            float4 A0 = srca[0], A1 = srca[1], A2 = srca[2], A3 = srca[3];
            float av[16] = {A0.x, A0.y, A0.z, A0.w, A1.x, A1.y, A1.z, A1.w,
                            A2.x, A2.y, A2.z, A2.w, A3.x, A3.y, A3.z, A3.w};
#pragma unroll
            for (int i = 0; i < 16; i++)
                Lm[(qt * 16 + i) * 64 + rr] = __logf(fminf(fmaxf(av[i], 0.f), 1.f) + 1e-6f);
        }
        __syncthreads();

        f32x4 sacc[4];
#pragma unroll
        for (int ni = 0; ni < 4; ni++) sacc[ni] = fzero;
        __builtin_amdgcn_s_setprio(1);
#pragma unroll
        for (int kk = 0; kk < 2; kk++) {
            int kb = (kk * 32 + lg * 8) * 2;
            int qrow = w * 16 + lr;
            bf16x8 aq = *(bf16x8*)((char*)Qs + qrow * 128 + (kb ^ ((qrow & 7) << 4)));
#pragma unroll
            for (int ni = 0; ni < 4; ni++) {
                int kr = ni * 16 + lr;
                bf16x8 bk = *(bf16x8*)((char*)Ks + kr * 128 + (kb ^ ((kr & 7) << 4)));
                sacc[ni] = __builtin_amdgcn_mfma_f32_16x16x32_bf16(aq, bk, sacc[ni], 0, 0, 0);
            }
        }
        __builtin_amdgcn_s_setprio(0);
        float sv[4][4], mx[4];
#pragma unroll
        for (int r = 0; r < 4; r++) {
            int q = w * 16 + lg * 4 + r;
            float m_ = -3e38f;
#pragma unroll
            for (int ni = 0; ni < 4; ni++) {
                float xx = sacc[ni][r] * 0.125f + Lm[q * 64 + ni * 16 + lr];
                sv[ni][r] = xx;
                m_ = fmaxf(m_, xx);
            }
            mx[r] = m_;
        }
#pragma unroll
        for (int off = 1; off < 16; off <<= 1)
#pragma unroll
            for (int r = 0; r < 4; r++) mx[r] = fmaxf(mx[r], __shfl_xor(mx[r], off, 64));
        float scale[4], lad[4];
#pragma unroll
        for (int r = 0; r < 4; r++) {
            float mn = fmaxf(m_run[r], mx[r]);
            scale[r] = __expf(m_run[r] - mn);
            m_run[r] = mn;
            float ls = 0.f;
#pragma unroll
            for (int ni = 0; ni < 4; ni++) {
                float p = __expf(sv[ni][r] - mn);
                sv[ni][r] = p;
                ls += p;
            }
            lad[r] = ls;
        }
#pragma unroll
        for (int off = 1; off < 16; off <<= 1)
#pragma unroll
            for (int r = 0; r < 4; r++) lad[r] += __shfl_xor(lad[r], off, 64);
#pragma unroll
        for (int r = 0; r < 4; r++) l_run[r] = l_run[r] * scale[r] + lad[r];
#pragma unroll
        for (int ni = 0; ni < 4; ni++) {
            f32x4 o = oacc[ni];
            o[0] *= scale[0]; o[1] *= scale[1]; o[2] *= scale[2]; o[3] *= scale[3];
            oacc[ni] = o;
        }
#pragma unroll
        for (int ni = 0; ni < 4; ni++)
#pragma unroll
            for (int r = 0; r < 4; r++) {
                int q = w * 16 + lg * 4 + r;
                int key = ni * 16 + lr;
                *(ushort*)((char*)Ps + q * 128 + ((key * 2) ^ ((q & 7) << 4))) = f2bf(sv[ni][r]);
            }
        __builtin_amdgcn_s_setprio(1);
#pragma unroll
        for (int kk = 0; kk < 2; kk++) {
            int kb = (kk * 32 + lg * 8) * 2;
            int prow = w * 16 + lr;
            bf16x8 ap = *(bf16x8*)((char*)Ps + prow * 128 + (kb ^ ((prow & 7) << 4)));
#pragma unroll
            for (int ni = 0; ni < 4; ni++) {
                int dk = ni * 16 + lr;
                bf16x8 bv = *(bf16x8*)((char*)Vt + dk * 128 + (kb ^ ((dk & 7) << 4)));
                oacc[ni] = __builtin_amdgcn_mfma_f32_16x16x32_bf16(ap, bv, oacc[ni], 0, 0, 0);
            }
        }
        __builtin_amdgcn_s_setprio(0);
    }
    const size_t ob = ((size_t)((b * 8 + h) * 4 + s)) * 4096;
#pragma unroll
    for (int ni = 0; ni < 4; ni++)
#pragma unroll
        for (int r = 0; r < 4; r++) {
            int q = w * 16 + lg * 4 + r;
            int dk = ni * 16 + lr;
            partO[ob + q * 64 + dk] = oacc[ni][r];
        }
    if (lr == 0) {
#pragma unroll
        for (int r = 0; r < 4; r++) {
            int q = w * 16 + lg * 4 + r;
            partML[((b * 8 + h) * 4 + s) * 128 + q * 2 + 0] = m_run[r];
            partML[((b * 8 + h) * 4 + s) * 128 + q * 2 + 1] = l_run[r];
        }
    }
}

// ---------------- merge split-KV partials (4), empty-slot fallback; finalizes counts ----------------
__global__ __launch_bounds__(256)
void combine_k(const float* __restrict__ partO, const float* __restrict__ partML,
               const float* __restrict__ cls, const float* __restrict__ cpart,
               float* __restrict__ cnt, float* __restrict__ emp,
               float* __restrict__ mout)
{
    const int bh = blockIdx.x, b = bh >> 3, h = bh & 7;
    __shared__ float Ms[64], Ls[64], Cs[64];
    const int tid = threadIdx.x;
    if (tid < 64) {
        float M = -3e38f;
#pragma unroll
        for (int s2 = 0; s2 < 4; s2++) M = fmaxf(M, partML[(bh * 4 + s2) * 128 + tid * 2]);
        float L = 0.f;
#pragma unroll
        for (int s2 = 0; s2 < 4; s2++) {
            float m_ = partML[(bh * 4 + s2) * 128 + tid * 2];
            float l_ = partML[(bh * 4 + s2) * 128 + tid * 2 + 1];
            L += l_ * __expf(m_ - M);
        }
        Ms[tid] = M; Ls[tid] = L;
        const float4* p = (const float4*)(cpart + ((size_t)b * 64 + tid) * 64);
        float cs = 0.f;
#pragma unroll
        for (int t = 0; t < 16; t++) {
            float4 f = p[t];
            cs += f.x + f.y + f.z + f.w;
        }
        Cs[tid] = cs;
        if (h == 0) {
            cnt[b * 64 + tid] = cs;
            emp[b * 64 + tid] = (cs <= 1e-6f) ? 1.f : 0.f;
        }
    }
    __syncthreads();
#pragma unroll
    for (int i = 0; i < 16; i++) {
        int e = i * 256 + tid;
        int q = e >> 6, dk = e & 63;
        float o = 0.f;
#pragma unroll
        for (int s2 = 0; s2 < 4; s2++) {
            float m_ = partML[(bh * 4 + s2) * 128 + q * 2];
            o += partO[(size_t)(bh * 4 + s2) * 4096 + e] * __expf(m_ - Ms[q]);
        }
        float val = o / (Ls[q] + 1e-8f);
        if (Cs[q] <= 1e-6f) val = cls[q * 512 + h * 64 + dk];
        mout[((size_t)b * 64 + q) * 512 + h * 64 + dk] = val;
    }
}

// ---------------- LN over rows of m (pre-FFN) ----------------
__global__ __launch_bounds__(256)
void ln_rows_k(const float* __restrict__ m, const float* __restrict__ g,
               const float* __restrict__ be, ushort* __restrict__ out)
{
    const int r = blockIdx.x, tid = threadIdx.x;
    float v0 = m[(size_t)r * 512 + tid];
    float v1 = m[(size_t)r * 512 + tid + 256];
    __shared__ float2 red[256];
    red[tid] = make_float2(v0 + v1, v0 * v0 + v1 * v1);
    __syncthreads();
    for (int s2 = 128; s2 > 0; s2 >>= 1) {
        if (tid < s2) {
            float2 o = red[tid + s2];
            float2 m2 = red[tid];
            red[tid] = make_float2(m2.x + o.x, m2.y + o.y);
        }
        __syncthreads();
    }
    float2 sr = red[0];
    float mu = sr.x * (1.f / 512.f);
    float var = sr.y * (1.f / 512.f) - mu * mu;
    float inv = rsqrtf(var + 1e-5f);
    out[(size_t)r * 512 + tid]       = f2bf((v0 - mu) * inv * g[tid] + be[tid]);
    out[(size_t)r * 512 + tid + 256] = f2bf((v1 - mu) * inv * g[tid + 256] + be[tid + 256]);
}

extern "C" void kernel_launch(void* const* d_in, const int* in_sizes, int n_in,
                              void* d_out, int out_size, void* d_ws, size_t ws_size,
                              hipStream_t stream)
{
    const float* x      = (const float*)d_in[0];
    const float* assign = (const float*)d_in[1];
    const float* E      = (const float*)d_in[2];
    const float* cls0   = (const float*)d_in[3];
    const float* e2dw   = (const float*)d_in[4];
    const float* e2db   = (const float*)d_in[5];
    const float* wq     = (const float*)d_in[6];
    const float* wqb    = (const float*)d_in[7];
    const float* wk     = (const float*)d_in[8];
    const float* wkb    = (const float*)d_in[9];
    const float* wv     = (const float*)d_in[10];
    const float* wvb    = (const float*)d_in[11];
    const float* lng    = (const float*)d_in[12];
    const float* lnbv   = (const float*)d_in[13];
    const float* fc1w   = (const float*)d_in[14];
    const float* fc1b   = (const float*)d_in[15];
    const float* fc2w   = (const float*)d_in[16];
    const float* fc2b   = (const float*)d_in[17];

    float* mout = (float*)d_out;
    float* cnt  = mout + (size_t)16 * 64 * 512;
    float* emp  = cnt + 16 * 64;

    char* ws = (char*)d_ws;
    size_t off = 0;
    auto alloc = [&](size_t bytes) -> char* {
        char* p = ws + off;
        off = (off + bytes + 255) & ~(size_t)255;
        return p;
    };
    float*  cls    = (float*) alloc((size_t)64 * 512 * 4);
    ushort* qbf    = (ushort*)alloc((size_t)64 * 512 * 2);
    ushort* wkvt   = (ushort*)alloc((size_t)1024 * 512 * 2);
    float*  biaskv = (float*) alloc((size_t)1024 * 4);
    ushort* fc1t   = (ushort*)alloc((size_t)2048 * 512 * 2);
    ushort* fc2t   = (ushort*)alloc((size_t)512 * 2048 * 2);
    ushort* kvb    = (ushort*)alloc((size_t)16 * 4096 * 1024 * 2);
    float*  partO  = (float*) alloc((size_t)16 * 8 * 4 * 64 * 64 * 4);
    float*  partML = (float*) alloc((size_t)16 * 8 * 4 * 128 * 4);
    float*  cpart  = (float*) alloc((size_t)16 * 64 * 64 * 4);
    ushort* lnbf   = (ushort*)alloc((size_t)1024 * 512 * 2);
    ushort* hhb    = (ushort*)alloc((size_t)1024 * 2048 * 2);
    float*  fcp    = (float*) alloc((size_t)4 * 1024 * 512 * 4);
    ushort* xb     = (ushort*)alloc((size_t)16 * 4096 * 512 * 2);
    const bool use_xb = (off <= ws_size);

    const int nxb = use_xb ? 16384 : 0;
    prep_all_k<<<nxb + 64 + 2564 + 1024, 256, 0, stream>>>(
        nxb, x, xb, E, cls0, e2dw, e2db, lng, lnbv, wq, wqb, cls, qbf,
        wk, wv, fc1w, fc2w, wkb, wvb, wkvt, fc1t, fc2t, biaskv,
        assign, cpart);

    if (use_xb) {
        gemm_k<0, 0, 1, 1024, 512, 512><<<4096, 512, 0, stream>>>(xb, wkvt, biaskv,
                                                                  kvb, nullptr, nullptr);
    } else {
        gemm_k<1, 0, 1, 1024, 512, 512><<<4096, 512, 0, stream>>>(x, wkvt, biaskv,
                                                                  kvb, nullptr, nullptr);
    }
    attn_k<<<dim3(8, 4, 16), 256, 0, stream>>>(qbf, kvb, assign, partO, partML);
    combine_k<<<128, 256, 0, stream>>>(partO, partML, cls, cpart, cnt, emp, mout);
    ln_rows_k<<<1024, 256, 0, stream>>>(mout, lng, lnbv, lnbf);
    gemm_k<0, 1, 0, 2048, 512, 512><<<dim3(8, 16), 512, 0, stream>>>(lnbf, fc1t, fc1b,
                                                                     hhb, nullptr, nullptr);
    gemm_k<0, 3, 0, 512, 512, 2048><<<dim3(8, 4, 4), 512, 0, stream>>>(hhb, fc2t, fc2b,
                                                                       nullptr, nullptr, fcp);
    combine2_k<<<2048, 256, 0, stream>>>(fcp, fc2b, mout);
}